// Round 11
// baseline (158.444 us; speedup 1.0000x reference)
//
#include <hip/hip_runtime.h>
#include <hip/hip_bf16.h>
#include <stdint.h>

// Problem constants (fixed by reference spec; dtypes f32/int32 verified over
// rounds 3-10 — bit-stable outputs; bounds-clamps retained as the safety net)
#define N_NODES   10000
#define D_FEAT    256
#define E_EDGES   320000
#define ROW_WORDS 313     // ceil(10000/32) bitmap words per row
#define ROW_STRIDE 320    // fallback plan: padded words per bitmap row
#define LIST_CAP  1024    // fallback plan: per-wave neighbor list capacity

// Bucketed-CSR build (primary plan, r9/r10-proven)
#define NB    250         // buckets
#define RPB   40          // rows per bucket (250*40 = 10000 exactly)
#define B_CAP 8192        // entries per bucket; mean 5120, sigma ~71 -> 30+ sigma

#define LDSTR 264         // f16 LDS row stride (256 + 8 pad; 528 B, 16B-aligned)

typedef __attribute__((ext_vector_type(4))) float float4v;   // 4 x f32
typedef _Float16 half8  __attribute__((ext_vector_type(8))); // 8 x f16 (4 VGPR)
typedef _Float16 half4v __attribute__((ext_vector_type(4))); // 4 x f16

__device__ __forceinline__ uint16_t f2bf(float f) {   // RNE, finite inputs
    union { float f; uint32_t u; } v; v.f = f;
    uint32_t r = v.u + 0x7fffu + ((v.u >> 16) & 1u);
    return (uint16_t)(r >> 16);
}
__device__ __forceinline__ float lo16(uint32_t u) {
    union { uint32_t u; float f; } v; v.u = u << 16; return v.f;
}
__device__ __forceinline__ float hi16(uint32_t u) {
    union { uint32_t u; float f; } v; v.u = u & 0xffff0000u; return v.f;
}

// ===========================================================================
// PRIMARY PLAN: sorted bucket fill -> LDS dedup CSR -> prescale -> fused
//               gather+MFMA (agg lives only in LDS)
// ===========================================================================

// ---------------------------------------------------------------------------
// P1: partition edge endpoints into 250 row-group buckets.
// r11: block-level LDS counting sort before the global write — r10 wrote
// 640k isolated 4B stores (~41 MB of dirty lines, r8's lesson); now each
// bucket's ~8 entries per block go out as one coalesced run.
// ---------------------------------------------------------------------------
__global__ void __launch_bounds__(1024)
fill_buckets(const int* __restrict__ ei, uint32_t* __restrict__ bucketbuf,
             uint32_t* __restrict__ cursors) {
    __shared__ uint32_t hist[256];
    __shared__ uint32_t lofs[256];     // inclusive scan of hist
    __shared__ uint32_t base_s[256];
    __shared__ uint32_t stage[2048];
    __shared__ uint16_t sbkt[2048];
    int t = threadIdx.x;
    if (t < 256) hist[t] = 0;
    __syncthreads();
    int e = blockIdx.x * 1024 + t;
    int b0 = -1, b1 = -1; uint32_t ent0 = 0, ent1 = 0, s0 = 0, s1 = 0;
    if (e < E_EDGES) {
        int s = ei[e], d = ei[E_EDGES + e];
        if ((uint32_t)s < N_NODES && (uint32_t)d < N_NODES) {
            b0 = s / RPB; ent0 = ((uint32_t)(s - b0 * RPB) << 14) | (uint32_t)d;
            b1 = d / RPB; ent1 = ((uint32_t)(d - b1 * RPB) << 14) | (uint32_t)s;
            s0 = atomicAdd(&hist[b0], 1u);
            s1 = atomicAdd(&hist[b1], 1u);
        }
    }
    __syncthreads();
    if (t < 256) lofs[t] = hist[t];
    __syncthreads();
    for (int d = 1; d < 256; d <<= 1) {              // Hillis-Steele inclusive
        uint32_t v = 0;
        if (t < 256 && t >= d) v = lofs[t - d];
        __syncthreads();
        if (t < 256) lofs[t] += v;
        __syncthreads();
    }
    if (t < 256) base_s[t] = hist[t] ? atomicAdd(&cursors[t], hist[t]) : 0u;
    // stage entries at exclusive-prefix + slot
    if (b0 >= 0) {
        uint32_t p0 = lofs[b0] - hist[b0] + s0;
        stage[p0] = ent0; sbkt[p0] = (uint16_t)b0;
        uint32_t p1 = lofs[b1] - hist[b1] + s1;
        stage[p1] = ent1; sbkt[p1] = (uint16_t)b1;
    }
    __syncthreads();
    uint32_t total = lofs[255];
    for (uint32_t idx = t; idx < total; idx += 1024) {
        uint32_t b = sbkt[idx];
        uint32_t pos = base_s[b] + (idx - (lofs[b] - hist[b]));
        if (pos < B_CAP) bucketbuf[(size_t)b * B_CAP + pos] = stage[idx];
    }
}

// ---------------------------------------------------------------------------
// P2: bucket entries -> LDS bitmap dedup -> deg/dinv -> compact global CSR
// (rows 4-entry aligned). One global atomic per block (r9/r10-proven).
// ---------------------------------------------------------------------------
__global__ void __launch_bounds__(1024)
bucket_to_csr(const uint32_t* __restrict__ bucketbuf,
              const uint32_t* __restrict__ cursors,
              uint32_t* __restrict__ gcursor,
              uint32_t* __restrict__ col, uint32_t* __restrict__ row_base,
              uint32_t* __restrict__ row_deg, float* __restrict__ dinv) {
    __shared__ uint32_t bm[RPB * ROW_WORDS];      // 50,080 B
    __shared__ uint32_t degs[RPB];
    __shared__ uint32_t rowoff[RPB];
    __shared__ uint32_t segbase;
    int b = blockIdx.x, t = threadIdx.x;
    for (int i = t; i < RPB * ROW_WORDS; i += 1024) bm[i] = 0;
    __syncthreads();
    uint32_t cnt = min(cursors[b], (uint32_t)B_CAP);
    const uint32_t* bb = bucketbuf + (size_t)b * B_CAP;
    for (uint32_t i = t; i < cnt; i += 1024) {
        uint32_t ent = bb[i];
        uint32_t lr = ent >> 14, d = ent & 0x3FFFu;
        atomicOr(&bm[lr * ROW_WORDS + (d >> 5)], 1u << (d & 31));
    }
    __syncthreads();
    int wv = t >> 6, lane = t & 63;               // 16 waves
    for (int r = wv; r < RPB; r += 16) {
        int pop = 0;
        #pragma unroll
        for (int k = 0; k < 5; k++) {
            int w = lane + 64 * k;
            if (w < ROW_WORDS) pop += __popc(bm[r * ROW_WORDS + w]);
        }
        #pragma unroll
        for (int off = 32; off > 0; off >>= 1) pop += __shfl_xor(pop, off, 64);
        if (lane == 0) degs[r] = (uint32_t)pop;
    }
    __syncthreads();
    if (t == 0) {
        uint32_t run = 0;
        for (int r = 0; r < RPB; r++) {
            rowoff[r] = run;
            run += (degs[r] + 3u) & ~3u;           // 4-entry align per row
        }
        segbase = atomicAdd(gcursor, run);
    }
    __syncthreads();
    int row0 = b * RPB;
    for (int r = wv; r < RPB; r += 16) {
        int gi = row0 + r;
        uint32_t base = segbase + rowoff[r];
        if (lane == 0) {
            row_base[gi] = base;
            row_deg[gi]  = degs[r];
            dinv[gi]     = 1.0f / sqrtf((float)(degs[r] + 1u));
        }
        uint32_t wb[5]; int tot = 0;
        #pragma unroll
        for (int k = 0; k < 5; k++) {
            int w = lane + 64 * k;
            uint32_t v = (w < ROW_WORDS) ? bm[r * ROW_WORDS + w] : 0u;
            wb[k] = v; tot += __popc(v);
        }
        int incl = tot;
        #pragma unroll
        for (int off = 1; off < 64; off <<= 1) {
            int v = __shfl_up(incl, off, 64);
            if (lane >= off) incl += v;
        }
        uint32_t p = base + (uint32_t)(incl - tot);
        #pragma unroll
        for (int k = 0; k < 5; k++) {
            uint32_t bits = wb[k];
            uint32_t cbase = (uint32_t)(lane + 64 * k) << 5;
            while (bits) {
                col[p++] = cbase + (uint32_t)__builtin_ctz(bits);
                bits &= bits - 1;
            }
        }
    }
}

// ---------------------------------------------------------------------------
// P3: xs_i = bf16(dinv_i * x_i)  — 5 MB L2-scale gather table (r8-proven).
// ---------------------------------------------------------------------------
__global__ void __launch_bounds__(256)
scale_cast(const float* __restrict__ dinv, const float* __restrict__ x,
           uint16_t* __restrict__ xs) {
    int wv = threadIdx.x >> 6, lane = threadIdx.x & 63;
    int i = blockIdx.x * 4 + wv;
    float di = dinv[i];
    float4v v = *(const float4v*)(x + (size_t)i * D_FEAT + lane * 4);
    uint2 o;
    o.x = (uint32_t)f2bf(di * v[0]) | ((uint32_t)f2bf(di * v[1]) << 16);
    o.y = (uint32_t)f2bf(di * v[2]) | ((uint32_t)f2bf(di * v[3]) << 16);
    *(uint2*)(xs + (size_t)i * D_FEAT + lane * 4) = o;
}

// ---------------------------------------------------------------------------
// P3b: wT[n][k] = f16(W[k][n]) — B operand for MFMA (128 KB, L2-resident).
// ---------------------------------------------------------------------------
__global__ void __launch_bounds__(256)
wcast(const float* __restrict__ w, _Float16* __restrict__ wt) {
    int k = blockIdx.x, n = threadIdx.x;
    wt[(size_t)n * D_FEAT + k] = (_Float16)w[(size_t)k * D_FEAT + n];
}

// ---------------------------------------------------------------------------
// P4 (r11 fusion): gather + GEMM in one kernel; agg never touches global.
// Block = 256 thr (4 waves) = 16 rows.
//  Phase A: wave wv gathers rows r0+wv, +4, +8, +12 (r7-10 proven 4-deep
//           pipeline), writes f16 agg row into LDS (stride 264: +8 pad).
//  Phase B: wave wv computes col-tiles wv*4..wv*4+3 via mfma_f32_16x16x32_f16
//           (A from LDS, hoisted per-k; B = wT rows from L2; layouts verified
//           end-to-end by r10's PASS at absmax 0.0039).
// ---------------------------------------------------------------------------
__global__ void __launch_bounds__(256)
spmm_gemm(const uint32_t* __restrict__ row_base, const uint32_t* __restrict__ row_deg,
          const float* __restrict__ dinv, const uint32_t* __restrict__ col,
          const uint16_t* __restrict__ xs, const _Float16* __restrict__ wt,
          float* __restrict__ out) {
    __shared__ __align__(16) _Float16 a_lds[16 * LDSTR];   // 8448 B
    int t = threadIdx.x, wv = t >> 6, lane = t & 63;
    int r0 = blockIdx.x * 16;
    size_t ch = (size_t)lane * 4;

    // ---- Phase A: gather 4 rows per wave ----
    for (int rr = wv; rr < 16; rr += 4) {
        int i = r0 + rr;
        uint32_t base = row_base[i], deg = row_deg[i];
        float di = dinv[i];
        float4v z = {0.f, 0.f, 0.f, 0.f};
        float4v acc0 = z, acc1 = z, acc2 = z, acc3 = z;
        uint32_t t4 = deg & ~3u;
        for (uint32_t k = 0; k < t4; k += 4) {
            uint4 jv = *(const uint4*)&col[base + k];   // wave-uniform bcast
            uint2 g0 = *(const uint2*)(xs + (size_t)jv.x * D_FEAT + ch);
            uint2 g1 = *(const uint2*)(xs + (size_t)jv.y * D_FEAT + ch);
            uint2 g2 = *(const uint2*)(xs + (size_t)jv.z * D_FEAT + ch);
            uint2 g3 = *(const uint2*)(xs + (size_t)jv.w * D_FEAT + ch);
            acc0[0] += lo16(g0.x); acc0[1] += hi16(g0.x); acc0[2] += lo16(g0.y); acc0[3] += hi16(g0.y);
            acc1[0] += lo16(g1.x); acc1[1] += hi16(g1.x); acc1[2] += lo16(g1.y); acc1[3] += hi16(g1.y);
            acc2[0] += lo16(g2.x); acc2[1] += hi16(g2.x); acc2[2] += lo16(g2.y); acc2[3] += hi16(g2.y);
            acc3[0] += lo16(g3.x); acc3[1] += hi16(g3.x); acc3[2] += lo16(g3.y); acc3[3] += hi16(g3.y);
        }
        for (uint32_t k = t4; k < deg; k++) {
            uint32_t j = col[base + k];
            uint2 g = *(const uint2*)(xs + (size_t)j * D_FEAT + ch);
            acc0[0] += lo16(g.x); acc0[1] += hi16(g.x); acc0[2] += lo16(g.y); acc0[3] += hi16(g.y);
        }
        uint2 gs = *(const uint2*)(xs + (size_t)i * D_FEAT + ch);   // +I term
        acc1[0] += lo16(gs.x); acc1[1] += hi16(gs.x); acc1[2] += lo16(gs.y); acc1[3] += hi16(gs.y);
        float4v acc = (acc0 + acc1) + (acc2 + acc3);
        half4v o = { (_Float16)(di * acc[0]), (_Float16)(di * acc[1]),
                     (_Float16)(di * acc[2]), (_Float16)(di * acc[3]) };
        *(half4v*)&a_lds[rr * LDSTR + lane * 4] = o;
    }
    __syncthreads();

    // ---- Phase B: 4 col-tiles per wave ----
    int quad = lane >> 4, r = lane & 15;
    int mbase = r0 + quad * 4;
    #pragma unroll
    for (int u = 0; u < 4; u++) {
        int ct = wv * 4 + u;                       // col tile 0..15
        const _Float16* pb = wt + (size_t)(ct * 16 + r) * D_FEAT + quad * 8;
        float4v acc = {0.f, 0.f, 0.f, 0.f};
        #pragma unroll
        for (int kk = 0; kk < D_FEAT; kk += 32) {
            half8 a = *(const half8*)&a_lds[r * LDSTR + kk + quad * 8];
            half8 b = *(const half8*)(pb + kk);
            acc = __builtin_amdgcn_mfma_f32_16x16x32_f16(a, b, acc, 0, 0, 0);
        }
        int colg = ct * 16 + r;
        #pragma unroll
        for (int v = 0; v < 4; v++)
            out[(size_t)(mbase + v) * D_FEAT + colg] = acc[v];
    }
}

// ===========================================================================
// FALLBACK PLAN (r7-proven, ~12.85 MB): global bitmap + popc + f32 gather
// ===========================================================================

__global__ void scatter_edges_fb(const int* __restrict__ ei,
                                 uint32_t* __restrict__ bitmap) {
    int e = blockIdx.x * blockDim.x + threadIdx.x;
    if (e >= E_EDGES) return;
    int s = ei[e], d = ei[E_EDGES + e];
    if ((uint32_t)s >= N_NODES || (uint32_t)d >= N_NODES) return;
    atomicOr(&bitmap[(size_t)s * ROW_STRIDE + (d >> 5)], 1u << (d & 31));
    atomicOr(&bitmap[(size_t)d * ROW_STRIDE + (s >> 5)], 1u << (s & 31));
}

__global__ void __launch_bounds__(256)
popc_dinv(const uint32_t* __restrict__ bitmap, float* __restrict__ dinv) {
    int wv = threadIdx.x >> 6, lane = threadIdx.x & 63;
    int i = blockIdx.x * 4 + wv;
    const uint32_t* rb = bitmap + (size_t)i * ROW_STRIDE;
    int pop = 0;
    #pragma unroll
    for (int k = 0; k < 5; k++) {
        int w = lane + 64 * k;
        if (w < ROW_WORDS) pop += __popc(rb[w]);
    }
    #pragma unroll
    for (int off = 32; off > 0; off >>= 1) pop += __shfl_xor(pop, off, 64);
    if (lane == 0) dinv[i] = 1.0f / sqrtf((float)(pop + 1));
}

__global__ void __launch_bounds__(256)
spmm_bitmap_fb(const uint32_t* __restrict__ bitmap, const float* __restrict__ dinv,
               const float* __restrict__ xf, float* __restrict__ agg) {
    __shared__ __align__(16) uint32_t lists[4][LIST_CAP];
    int wv = threadIdx.x >> 6, lane = threadIdx.x & 63;
    int i = blockIdx.x * 4 + wv;
    uint32_t* list = lists[wv];
    const uint32_t* rb = bitmap + (size_t)i * ROW_STRIDE;

    uint32_t wbits[5]; int tot = 0;
    #pragma unroll
    for (int k = 0; k < 5; k++) {
        int w = lane + 64 * k;
        uint32_t b = (w < ROW_WORDS) ? rb[w] : 0u;
        wbits[k] = b;
        tot += __popc(b);
    }
    int incl = tot;
    #pragma unroll
    for (int off = 1; off < 64; off <<= 1) {
        int v = __shfl_up(incl, off, 64);
        if (lane >= off) incl += v;
    }
    uint32_t p = (uint32_t)(incl - tot);
    uint32_t deg = (uint32_t)__shfl(incl, 63, 64);
    #pragma unroll
    for (int k = 0; k < 5; k++) {
        uint32_t bits = wbits[k];
        uint32_t base = (uint32_t)(lane + 64 * k) << 5;
        while (bits) {
            if (p < LIST_CAP) list[p] = base + (uint32_t)__builtin_ctz(bits);
            p++;
            bits &= bits - 1;
        }
    }
    if (deg > LIST_CAP) deg = LIST_CAP;

    float di = dinv[i];
    float4v z = {0.f, 0.f, 0.f, 0.f};
    float4v acc0 = z, acc1 = z, acc2 = z, acc3 = z;
    float4v sv = *(const float4v*)(xf + (size_t)i * D_FEAT + lane * 4);
    uint32_t t4 = deg & ~3u;
    for (uint32_t k = 0; k < t4; k += 4) {
        uint4 jv = *(const uint4*)&list[k];
        float d0 = dinv[jv.x], d1 = dinv[jv.y], d2 = dinv[jv.z], d3 = dinv[jv.w];
        float4v v0 = *(const float4v*)(xf + (size_t)jv.x * D_FEAT + lane * 4);
        float4v v1 = *(const float4v*)(xf + (size_t)jv.y * D_FEAT + lane * 4);
        float4v v2 = *(const float4v*)(xf + (size_t)jv.z * D_FEAT + lane * 4);
        float4v v3 = *(const float4v*)(xf + (size_t)jv.w * D_FEAT + lane * 4);
        acc0 += d0 * v0; acc1 += d1 * v1; acc2 += d2 * v2; acc3 += d3 * v3;
    }
    for (uint32_t k = t4; k < deg; k++) {
        uint32_t j = list[k];
        acc0 += dinv[j] * (*(const float4v*)(xf + (size_t)j * D_FEAT + lane * 4));
    }
    float4v acc = (acc0 + acc1) + (acc2 + acc3) + di * sv;
    *(float4v*)(agg + (size_t)i * D_FEAT + lane * 4) = di * acc;
}

// Fallback epilogue GEMM (in place on d_out) — r9-proven VALU version.
__global__ void __launch_bounds__(256)
gemm_valu(float* __restrict__ io, const float* __restrict__ wf) {
    __shared__ __align__(16) float a_lds[16 * D_FEAT];
    int c = threadIdx.x;
    int r0 = blockIdx.x * 16;
    for (int idx = c; idx < 16 * D_FEAT; idx += 256)
        a_lds[idx] = io[(size_t)r0 * D_FEAT + idx];
    __syncthreads();
    float acc[16];
    #pragma unroll
    for (int r = 0; r < 16; r++) acc[r] = 0.f;
    for (int k0 = 0; k0 < D_FEAT; k0 += 4) {
        float w0 = wf[(size_t)(k0 + 0) * D_FEAT + c];
        float w1 = wf[(size_t)(k0 + 1) * D_FEAT + c];
        float w2 = wf[(size_t)(k0 + 2) * D_FEAT + c];
        float w3 = wf[(size_t)(k0 + 3) * D_FEAT + c];
        #pragma unroll
        for (int r = 0; r < 16; r++) {
            float4v av = *(const float4v*)&a_lds[r * D_FEAT + k0];
            acc[r] = fmaf(av[3], w3, fmaf(av[2], w2,
                     fmaf(av[1], w1, fmaf(av[0], w0, acc[r]))));
        }
    }
    #pragma unroll
    for (int r = 0; r < 16; r++)
        io[(size_t)(r0 + r) * D_FEAT + c] = acc[r];
}

// ---------------------------------------------------------------------------
extern "C" void kernel_launch(void* const* d_in, const int* in_sizes, int n_in,
                              void* d_out, int out_size, void* d_ws, size_t ws_size,
                              hipStream_t stream) {
    const float* x  = (const float*)d_in[0];     // f32 [N, 256]
    const int*   ei = (const int*)d_in[1];       // int32 [2, E]
    const float* w  = (const float*)d_in[2];     // f32 [256, 256]
    float* out = (float*)d_out;                  // f32 [N, 256]
    uint8_t* ws = (uint8_t*)d_ws;

    // Primary layout (16.29 MB; ws >= 18 MB proven by r8-r10):
    //   bucketbuf @ 0          : 8,192,000
    //   cursors   @ 8,192,000  : 2,048       (250 cursors + gcursor)
    //   row_base  @ 8,194,048  : 40,000
    //   row_deg   @ 8,234,048  : 40,000
    //   dinv      @ 8,274,048  : 40,000
    //   xs        @ 8,314,048  : 5,120,000   (bf16 prescaled x)
    //   col       @ 13,434,048 : 2,720,000
    //   wT(f16)   @ 16,154,048 : 131,072
    const size_t CUR_OFF  = 8192000;
    const size_t RB_OFF   = 8194048;
    const size_t RD_OFF   = 8234048;
    const size_t DI_OFF   = 8274048;
    const size_t XS_OFF   = 8314048;
    const size_t COL_OFF  = 13434048;
    const size_t WT_OFF   = 16154048;
    const size_t NEED_NEW = 16285120;
    const size_t NEED_FB  = 12840000;

    if (ws_size >= NEED_NEW) {
        uint32_t* bucketbuf = (uint32_t*)ws;
        uint32_t* cursors   = (uint32_t*)(ws + CUR_OFF);
        uint32_t* row_base  = (uint32_t*)(ws + RB_OFF);
        uint32_t* row_deg   = (uint32_t*)(ws + RD_OFF);
        float*    dinv      = (float*)(ws + DI_OFF);
        uint16_t* xs        = (uint16_t*)(ws + XS_OFF);
        uint32_t* col       = (uint32_t*)(ws + COL_OFF);
        _Float16* wt        = (_Float16*)(ws + WT_OFF);

        hipMemsetAsync(cursors, 0, 2048, stream);    // cursors + gcursor only
        fill_buckets <<<(E_EDGES + 1023) / 1024, 1024, 0, stream>>>(ei, bucketbuf, cursors);
        bucket_to_csr<<<NB, 1024, 0, stream>>>(bucketbuf, cursors, &cursors[NB],
                                               col, row_base, row_deg, dinv);
        wcast        <<<D_FEAT, D_FEAT, 0, stream>>>(w, wt);
        scale_cast   <<<N_NODES / 4, 256, 0, stream>>>(dinv, x, xs);
        spmm_gemm    <<<N_NODES / 16, 256, 0, stream>>>(row_base, row_deg, dinv,
                                                        col, xs, wt, out);
    } else if (ws_size >= NEED_FB) {
        uint32_t* bitmap = (uint32_t*)ws;
        float*    dinv   = (float*)(ws + 12800000);

        hipMemsetAsync(bitmap, 0, 12800000, stream);
        scatter_edges_fb<<<(E_EDGES + 255) / 256, 256, 0, stream>>>(ei, bitmap);
        popc_dinv      <<<N_NODES / 4, 256, 0, stream>>>(bitmap, dinv);
        spmm_bitmap_fb <<<N_NODES / 4, 256, 0, stream>>>(bitmap, dinv, x, out);
        gemm_valu      <<<N_NODES / 16, 256, 0, stream>>>(out, w);
    }
    // else: ws too small for any safe plan — no-op (never observed).
}

// Round 12
// 142.659 us; speedup vs baseline: 1.1107x; 1.1107x over previous
//
#include <hip/hip_runtime.h>
#include <hip/hip_bf16.h>
#include <stdint.h>

// Problem constants (fixed by reference spec; dtypes f32/int32 verified over
// rounds 3-11 — bit-stable outputs; bounds-clamps retained as the safety net)
#define N_NODES   10000
#define D_FEAT    256
#define E_EDGES   320000
#define ROW_WORDS 313     // ceil(10000/32) bitmap words per row
#define ROW_STRIDE 320    // fallback plan: padded words per bitmap row
#define LIST_CAP  1024    // fallback plan: per-wave neighbor list capacity

// Bucketed-CSR build (primary plan, r9-r11 proven)
#define NB     250        // buckets
#define RPB    40         // rows per bucket (250*40 = 10000 exactly)
#define B_CAP  8192       // entries per bucket; mean 5120, sigma ~71 -> 30+ sigma
#define NBLK_E 313        // edge blocks in fill_buckets ((320000+1023)/1024)
#define NBLK_W 64         // wcast blocks appended to fill_buckets (4 k each)

typedef __attribute__((ext_vector_type(4))) float float4v;   // 4 x f32
typedef _Float16 half8  __attribute__((ext_vector_type(8))); // 8 x f16 (4 VGPR)
typedef _Float16 half4v __attribute__((ext_vector_type(4))); // 4 x f16

__device__ __forceinline__ uint16_t f2bf(float f) {   // RNE, finite inputs
    union { float f; uint32_t u; } v; v.f = f;
    uint32_t r = v.u + 0x7fffu + ((v.u >> 16) & 1u);
    return (uint16_t)(r >> 16);
}
__device__ __forceinline__ float lo16(uint32_t u) {
    union { uint32_t u; float f; } v; v.u = u << 16; return v.f;
}
__device__ __forceinline__ float hi16(uint32_t u) {
    union { uint32_t u; float f; } v; v.u = u & 0xffff0000u; return v.f;
}

// ===========================================================================
// PRIMARY PLAN: counting-sort bucket fill (+fused W transpose) ->
//   LDS dedup CSR (+fused prescale) -> wave-per-row gather -> MFMA GEMM.
// r11 lesson: NEVER trade wave count for locality in the latency-bound
// gather (fused 2500-wave version ran 68 us vs ~35 for 10000-wave r10).
// ===========================================================================

// ---------------------------------------------------------------------------
// P1: blocks [0,313): partition edges into 250 row-group buckets via block-
// level LDS counting sort (r11: coalesced runs instead of 640k 4B scatters).
//     blocks [313,377): wT[n][k] = f16(W[k][n]), LDS-staged, coalesced 8B
// stores (fused to save a dispatch).
// ---------------------------------------------------------------------------
__global__ void __launch_bounds__(1024)
fill_buckets(const int* __restrict__ ei, uint32_t* __restrict__ bucketbuf,
             uint32_t* __restrict__ cursors,
             const float* __restrict__ w, _Float16* __restrict__ wt) {
    __shared__ uint32_t hist[256];
    __shared__ uint32_t lofs[256];     // inclusive scan of hist
    __shared__ uint32_t base_s[256];
    __shared__ uint32_t stage[2048];   // also reused as f32[1024] by wcast
    __shared__ uint16_t sbkt[2048];
    int t = threadIdx.x;

    if (blockIdx.x >= NBLK_E) {        // ---- fused wcast blocks ----
        int kb = (blockIdx.x - NBLK_E) * 4;
        int k = kb + (t >> 8), n = t & 255;
        float* st = (float*)stage;     // 4 KB staging
        st[(n << 2) | (t >> 8)] = w[(size_t)k * D_FEAT + n];
        __syncthreads();
        if (t < 256) {
            half4v o = { (_Float16)st[t * 4 + 0], (_Float16)st[t * 4 + 1],
                         (_Float16)st[t * 4 + 2], (_Float16)st[t * 4 + 3] };
            *(half4v*)&wt[(size_t)t * D_FEAT + kb] = o;
        }
        return;
    }

    if (t < 256) hist[t] = 0;
    __syncthreads();
    int e = blockIdx.x * 1024 + t;
    int b0 = -1, b1 = -1; uint32_t ent0 = 0, ent1 = 0, s0 = 0, s1 = 0;
    if (e < E_EDGES) {
        int s = ei[e], d = ei[E_EDGES + e];
        if ((uint32_t)s < N_NODES && (uint32_t)d < N_NODES) {
            b0 = s / RPB; ent0 = ((uint32_t)(s - b0 * RPB) << 14) | (uint32_t)d;
            b1 = d / RPB; ent1 = ((uint32_t)(d - b1 * RPB) << 14) | (uint32_t)s;
            s0 = atomicAdd(&hist[b0], 1u);
            s1 = atomicAdd(&hist[b1], 1u);
        }
    }
    __syncthreads();
    if (t < 256) lofs[t] = hist[t];
    __syncthreads();
    for (int d = 1; d < 256; d <<= 1) {              // Hillis-Steele inclusive
        uint32_t v = 0;
        if (t < 256 && t >= d) v = lofs[t - d];
        __syncthreads();
        if (t < 256) lofs[t] += v;
        __syncthreads();
    }
    if (t < 256) base_s[t] = hist[t] ? atomicAdd(&cursors[t], hist[t]) : 0u;
    if (b0 >= 0) {
        uint32_t p0 = lofs[b0] - hist[b0] + s0;
        stage[p0] = ent0; sbkt[p0] = (uint16_t)b0;
        uint32_t p1 = lofs[b1] - hist[b1] + s1;
        stage[p1] = ent1; sbkt[p1] = (uint16_t)b1;
    }
    __syncthreads();
    uint32_t total = lofs[255];
    for (uint32_t idx = t; idx < total; idx += 1024) {
        uint32_t b = sbkt[idx];
        uint32_t pos = base_s[b] + (idx - (lofs[b] - hist[b]));
        if (pos < B_CAP) bucketbuf[(size_t)b * B_CAP + pos] = stage[idx];
    }
}

// ---------------------------------------------------------------------------
// P2: bucket entries -> LDS bitmap dedup -> deg/dinv -> compact global CSR
// (rows 4-entry aligned; one global atomic per block) + FUSED prescale:
// this block owns rows b*40..b*40+39, so it also writes xs = bf16(dinv*x)
// for them (kills the separate 2500-block scale_cast dispatch).
// ---------------------------------------------------------------------------
__global__ void __launch_bounds__(1024)
bucket_to_csr(const uint32_t* __restrict__ bucketbuf,
              const uint32_t* __restrict__ cursors,
              uint32_t* __restrict__ gcursor,
              uint32_t* __restrict__ col, uint32_t* __restrict__ row_base,
              uint32_t* __restrict__ row_deg, float* __restrict__ dinv,
              const float* __restrict__ x, uint16_t* __restrict__ xs) {
    __shared__ uint32_t bm[RPB * ROW_WORDS];      // 50,080 B
    __shared__ uint32_t degs[RPB];
    __shared__ uint32_t rowoff[RPB];
    __shared__ uint32_t segbase;
    int b = blockIdx.x, t = threadIdx.x;
    for (int i = t; i < RPB * ROW_WORDS; i += 1024) bm[i] = 0;
    __syncthreads();
    uint32_t cnt = min(cursors[b], (uint32_t)B_CAP);
    const uint32_t* bb = bucketbuf + (size_t)b * B_CAP;
    for (uint32_t i = t; i < cnt; i += 1024) {
        uint32_t ent = bb[i];
        uint32_t lr = ent >> 14, d = ent & 0x3FFFu;
        atomicOr(&bm[lr * ROW_WORDS + (d >> 5)], 1u << (d & 31));
    }
    __syncthreads();
    int wv = t >> 6, lane = t & 63;               // 16 waves
    for (int r = wv; r < RPB; r += 16) {
        int pop = 0;
        #pragma unroll
        for (int k = 0; k < 5; k++) {
            int w = lane + 64 * k;
            if (w < ROW_WORDS) pop += __popc(bm[r * ROW_WORDS + w]);
        }
        #pragma unroll
        for (int off = 32; off > 0; off >>= 1) pop += __shfl_xor(pop, off, 64);
        if (lane == 0) degs[r] = (uint32_t)pop;
    }
    __syncthreads();
    if (t == 0) {
        uint32_t run = 0;
        for (int r = 0; r < RPB; r++) {
            rowoff[r] = run;
            run += (degs[r] + 3u) & ~3u;           // 4-entry align per row
        }
        segbase = atomicAdd(gcursor, run);
    }
    __syncthreads();
    int row0 = b * RPB;
    for (int r = wv; r < RPB; r += 16) {
        int gi = row0 + r;
        uint32_t base = segbase + rowoff[r];
        float di = 1.0f / sqrtf((float)(degs[r] + 1u));
        if (lane == 0) {
            row_base[gi] = base;
            row_deg[gi]  = degs[r];
            dinv[gi]     = di;
        }
        // ---- fused prescale: xs[gi] = bf16(di * x[gi]) (coalesced) ----
        float4v xv = *(const float4v*)(x + (size_t)gi * D_FEAT + lane * 4);
        uint2 o;
        o.x = (uint32_t)f2bf(di * xv[0]) | ((uint32_t)f2bf(di * xv[1]) << 16);
        o.y = (uint32_t)f2bf(di * xv[2]) | ((uint32_t)f2bf(di * xv[3]) << 16);
        *(uint2*)(xs + (size_t)gi * D_FEAT + lane * 4) = o;
        // ---- expand set bits -> col[base ...] ----
        uint32_t wb[5]; int tot = 0;
        #pragma unroll
        for (int k = 0; k < 5; k++) {
            int w = lane + 64 * k;
            uint32_t v = (w < ROW_WORDS) ? bm[r * ROW_WORDS + w] : 0u;
            wb[k] = v; tot += __popc(v);
        }
        int incl = tot;
        #pragma unroll
        for (int off = 1; off < 64; off <<= 1) {
            int v = __shfl_up(incl, off, 64);
            if (lane >= off) incl += v;
        }
        uint32_t p = base + (uint32_t)(incl - tot);
        #pragma unroll
        for (int k = 0; k < 5; k++) {
            uint32_t bits = wb[k];
            uint32_t cbase = (uint32_t)(lane + 64 * k) << 5;
            while (bits) {
                col[p++] = cbase + (uint32_t)__builtin_ctz(bits);
                bits &= bits - 1;
            }
        }
    }
}

// ---------------------------------------------------------------------------
// P3: aggregation, wave-per-row (10000 waves — r11 lesson: keep max wave
// parallelism in the latency-bound gather). 4 independent gather streams.
// agg (f16, GEMM A operand) -> ws (bucketbuf region, dead by now).
// ---------------------------------------------------------------------------
__global__ void __launch_bounds__(256)
spmm_csr(const uint32_t* __restrict__ row_base, const uint32_t* __restrict__ row_deg,
         const float* __restrict__ dinv, const uint32_t* __restrict__ col,
         const uint16_t* __restrict__ xs, _Float16* __restrict__ aggh) {
    int wv = threadIdx.x >> 6, lane = threadIdx.x & 63;
    int i = blockIdx.x * 4 + wv;
    uint32_t base = row_base[i], deg = row_deg[i];
    float di = dinv[i];
    float4v z = {0.f, 0.f, 0.f, 0.f};
    float4v acc0 = z, acc1 = z, acc2 = z, acc3 = z;
    size_t ch = (size_t)lane * 4;
    uint32_t t4 = deg & ~3u;
    for (uint32_t t = 0; t < t4; t += 4) {
        uint4 jv = *(const uint4*)&col[base + t];    // wave-uniform broadcast
        uint2 g0 = *(const uint2*)(xs + (size_t)jv.x * D_FEAT + ch);
        uint2 g1 = *(const uint2*)(xs + (size_t)jv.y * D_FEAT + ch);
        uint2 g2 = *(const uint2*)(xs + (size_t)jv.z * D_FEAT + ch);
        uint2 g3 = *(const uint2*)(xs + (size_t)jv.w * D_FEAT + ch);
        acc0[0] += lo16(g0.x); acc0[1] += hi16(g0.x); acc0[2] += lo16(g0.y); acc0[3] += hi16(g0.y);
        acc1[0] += lo16(g1.x); acc1[1] += hi16(g1.x); acc1[2] += lo16(g1.y); acc1[3] += hi16(g1.y);
        acc2[0] += lo16(g2.x); acc2[1] += hi16(g2.x); acc2[2] += lo16(g2.y); acc2[3] += hi16(g2.y);
        acc3[0] += lo16(g3.x); acc3[1] += hi16(g3.x); acc3[2] += lo16(g3.y); acc3[3] += hi16(g3.y);
    }
    for (uint32_t t = t4; t < deg; t++) {
        uint32_t j = col[base + t];
        uint2 g = *(const uint2*)(xs + (size_t)j * D_FEAT + ch);
        acc0[0] += lo16(g.x); acc0[1] += hi16(g.x); acc0[2] += lo16(g.y); acc0[3] += hi16(g.y);
    }
    uint2 gs = *(const uint2*)(xs + (size_t)i * D_FEAT + ch);   // +I self term
    acc1[0] += lo16(gs.x); acc1[1] += hi16(gs.x); acc1[2] += lo16(gs.y); acc1[3] += hi16(gs.y);
    float4v acc = (acc0 + acc1) + (acc2 + acc3);
    half4v o = { (_Float16)(di * acc[0]), (_Float16)(di * acc[1]),
                 (_Float16)(di * acc[2]), (_Float16)(di * acc[3]) };
    *(half4v*)(aggh + (size_t)i * D_FEAT + ch) = o;
}

// ---------------------------------------------------------------------------
// P4: out = aggh @ W via mfma_f32_16x16x32_f16 (r10-proven; layouts verified
// end-to-end by r10's PASS). One wave per 16x16 tile, 8 MFMAs over K=256.
// ---------------------------------------------------------------------------
__global__ void __launch_bounds__(256)
gemm_mfma(const _Float16* __restrict__ aggh, const _Float16* __restrict__ wt,
          float* __restrict__ out) {
    int t = threadIdx.x;
    int wv = t >> 6, lane = t & 63;
    int quad = lane >> 4, r = lane & 15;
    int bx = blockIdx.x;                     // row tile (16 rows)
    int ct = blockIdx.y * 4 + wv;            // col tile (16 cols)

    const _Float16* pa = aggh + (size_t)(bx * 16 + r) * D_FEAT + quad * 8;
    const _Float16* pb = wt   + (size_t)(ct * 16 + r) * D_FEAT + quad * 8;

    float4v acc = {0.f, 0.f, 0.f, 0.f};
    #pragma unroll
    for (int kk = 0; kk < D_FEAT; kk += 32) {
        half8 a = *(const half8*)(pa + kk);
        half8 b = *(const half8*)(pb + kk);
        acc = __builtin_amdgcn_mfma_f32_16x16x32_f16(a, b, acc, 0, 0, 0);
    }
    int mbase = bx * 16 + quad * 4;
    int colg  = ct * 16 + r;
    #pragma unroll
    for (int u = 0; u < 4; u++)
        out[(size_t)(mbase + u) * D_FEAT + colg] = acc[u];
}

// ===========================================================================
// FALLBACK PLAN (r7-proven, ~12.85 MB): global bitmap + popc + f32 gather
// ===========================================================================

__global__ void scatter_edges_fb(const int* __restrict__ ei,
                                 uint32_t* __restrict__ bitmap) {
    int e = blockIdx.x * blockDim.x + threadIdx.x;
    if (e >= E_EDGES) return;
    int s = ei[e], d = ei[E_EDGES + e];
    if ((uint32_t)s >= N_NODES || (uint32_t)d >= N_NODES) return;
    atomicOr(&bitmap[(size_t)s * ROW_STRIDE + (d >> 5)], 1u << (d & 31));
    atomicOr(&bitmap[(size_t)d * ROW_STRIDE + (s >> 5)], 1u << (s & 31));
}

__global__ void __launch_bounds__(256)
popc_dinv(const uint32_t* __restrict__ bitmap, float* __restrict__ dinv) {
    int wv = threadIdx.x >> 6, lane = threadIdx.x & 63;
    int i = blockIdx.x * 4 + wv;
    const uint32_t* rb = bitmap + (size_t)i * ROW_STRIDE;
    int pop = 0;
    #pragma unroll
    for (int k = 0; k < 5; k++) {
        int w = lane + 64 * k;
        if (w < ROW_WORDS) pop += __popc(rb[w]);
    }
    #pragma unroll
    for (int off = 32; off > 0; off >>= 1) pop += __shfl_xor(pop, off, 64);
    if (lane == 0) dinv[i] = 1.0f / sqrtf((float)(pop + 1));
}

__global__ void __launch_bounds__(256)
spmm_bitmap_fb(const uint32_t* __restrict__ bitmap, const float* __restrict__ dinv,
               const float* __restrict__ xf, float* __restrict__ agg) {
    __shared__ __align__(16) uint32_t lists[4][LIST_CAP];
    int wv = threadIdx.x >> 6, lane = threadIdx.x & 63;
    int i = blockIdx.x * 4 + wv;
    uint32_t* list = lists[wv];
    const uint32_t* rb = bitmap + (size_t)i * ROW_STRIDE;

    uint32_t wbits[5]; int tot = 0;
    #pragma unroll
    for (int k = 0; k < 5; k++) {
        int w = lane + 64 * k;
        uint32_t b = (w < ROW_WORDS) ? rb[w] : 0u;
        wbits[k] = b;
        tot += __popc(b);
    }
    int incl = tot;
    #pragma unroll
    for (int off = 1; off < 64; off <<= 1) {
        int v = __shfl_up(incl, off, 64);
        if (lane >= off) incl += v;
    }
    uint32_t p = (uint32_t)(incl - tot);
    uint32_t deg = (uint32_t)__shfl(incl, 63, 64);
    #pragma unroll
    for (int k = 0; k < 5; k++) {
        uint32_t bits = wbits[k];
        uint32_t base = (uint32_t)(lane + 64 * k) << 5;
        while (bits) {
            if (p < LIST_CAP) list[p] = base + (uint32_t)__builtin_ctz(bits);
            p++;
            bits &= bits - 1;
        }
    }
    if (deg > LIST_CAP) deg = LIST_CAP;

    float di = dinv[i];
    float4v z = {0.f, 0.f, 0.f, 0.f};
    float4v acc0 = z, acc1 = z, acc2 = z, acc3 = z;
    float4v sv = *(const float4v*)(xf + (size_t)i * D_FEAT + lane * 4);
    uint32_t t4 = deg & ~3u;
    for (uint32_t k = 0; k < t4; k += 4) {
        uint4 jv = *(const uint4*)&list[k];
        float d0 = dinv[jv.x], d1 = dinv[jv.y], d2 = dinv[jv.z], d3 = dinv[jv.w];
        float4v v0 = *(const float4v*)(xf + (size_t)jv.x * D_FEAT + lane * 4);
        float4v v1 = *(const float4v*)(xf + (size_t)jv.y * D_FEAT + lane * 4);
        float4v v2 = *(const float4v*)(xf + (size_t)jv.z * D_FEAT + lane * 4);
        float4v v3 = *(const float4v*)(xf + (size_t)jv.w * D_FEAT + lane * 4);
        acc0 += d0 * v0; acc1 += d1 * v1; acc2 += d2 * v2; acc3 += d3 * v3;
    }
    for (uint32_t k = t4; k < deg; k++) {
        uint32_t j = list[k];
        acc0 += dinv[j] * (*(const float4v*)(xf + (size_t)j * D_FEAT + lane * 4));
    }
    float4v acc = (acc0 + acc1) + (acc2 + acc3) + di * sv;
    *(float4v*)(agg + (size_t)i * D_FEAT + lane * 4) = di * acc;
}

// Fallback epilogue GEMM (in place on d_out) — r9-proven VALU version.
__global__ void __launch_bounds__(256)
gemm_valu(float* __restrict__ io, const float* __restrict__ wf) {
    __shared__ __align__(16) float a_lds[16 * D_FEAT];
    int c = threadIdx.x;
    int r0 = blockIdx.x * 16;
    for (int idx = c; idx < 16 * D_FEAT; idx += 256)
        a_lds[idx] = io[(size_t)r0 * D_FEAT + idx];
    __syncthreads();
    float acc[16];
    #pragma unroll
    for (int r = 0; r < 16; r++) acc[r] = 0.f;
    for (int k0 = 0; k0 < D_FEAT; k0 += 4) {
        float w0 = wf[(size_t)(k0 + 0) * D_FEAT + c];
        float w1 = wf[(size_t)(k0 + 1) * D_FEAT + c];
        float w2 = wf[(size_t)(k0 + 2) * D_FEAT + c];
        float w3 = wf[(size_t)(k0 + 3) * D_FEAT + c];
        #pragma unroll
        for (int r = 0; r < 16; r++) {
            float4v av = *(const float4v*)&a_lds[r * D_FEAT + k0];
            acc[r] = fmaf(av[3], w3, fmaf(av[2], w2,
                     fmaf(av[1], w1, fmaf(av[0], w0, acc[r]))));
        }
    }
    #pragma unroll
    for (int r = 0; r < 16; r++)
        io[(size_t)(r0 + r) * D_FEAT + c] = acc[r];
}

// ---------------------------------------------------------------------------
extern "C" void kernel_launch(void* const* d_in, const int* in_sizes, int n_in,
                              void* d_out, int out_size, void* d_ws, size_t ws_size,
                              hipStream_t stream) {
    const float* x  = (const float*)d_in[0];     // f32 [N, 256]
    const int*   ei = (const int*)d_in[1];       // int32 [2, E]
    const float* w  = (const float*)d_in[2];     // f32 [256, 256]
    float* out = (float*)d_out;                  // f32 [N, 256]
    uint8_t* ws = (uint8_t*)d_ws;

    // Primary layout (16.29 MB; ws >= 18 MB proven by r8-r11):
    //   bucketbuf @ 0          : 8,192,000  -- dead after bucket_to_csr;
    //   aggh      @ 0          : 5,120,000     reused as f16 agg (A operand)
    //   cursors   @ 8,192,000  : 2,048      (250 cursors + gcursor)
    //   row_base  @ 8,194,048  : 40,000
    //   row_deg   @ 8,234,048  : 40,000
    //   dinv      @ 8,274,048  : 40,000
    //   xs        @ 8,314,048  : 5,120,000  (bf16 prescaled x)
    //   col       @ 13,434,048 : 2,720,000
    //   wT(f16)   @ 16,154,048 : 131,072
    const size_t CUR_OFF  = 8192000;
    const size_t RB_OFF   = 8194048;
    const size_t RD_OFF   = 8234048;
    const size_t DI_OFF   = 8274048;
    const size_t XS_OFF   = 8314048;
    const size_t COL_OFF  = 13434048;
    const size_t WT_OFF   = 16154048;
    const size_t NEED_NEW = 16285120;
    const size_t NEED_FB  = 12840000;

    if (ws_size >= NEED_NEW) {
        uint32_t* bucketbuf = (uint32_t*)ws;
        _Float16* aggh      = (_Float16*)ws;         // reuse (sequential kernels)
        uint32_t* cursors   = (uint32_t*)(ws + CUR_OFF);
        uint32_t* row_base  = (uint32_t*)(ws + RB_OFF);
        uint32_t* row_deg   = (uint32_t*)(ws + RD_OFF);
        float*    dinv      = (float*)(ws + DI_OFF);
        uint16_t* xs        = (uint16_t*)(ws + XS_OFF);
        uint32_t* col       = (uint32_t*)(ws + COL_OFF);
        _Float16* wt        = (_Float16*)(ws + WT_OFF);

        hipMemsetAsync(cursors, 0, 2048, stream);    // cursors + gcursor only
        fill_buckets <<<NBLK_E + NBLK_W, 1024, 0, stream>>>(ei, bucketbuf, cursors, w, wt);
        bucket_to_csr<<<NB, 1024, 0, stream>>>(bucketbuf, cursors, &cursors[NB],
                                               col, row_base, row_deg, dinv, x, xs);
        spmm_csr     <<<N_NODES / 4, 256, 0, stream>>>(row_base, row_deg, dinv, col, xs, aggh);
        gemm_mfma    <<<dim3(N_NODES / 16, 4), 256, 0, stream>>>(aggh, wt, out);
    } else if (ws_size >= NEED_FB) {
        uint32_t* bitmap = (uint32_t*)ws;
        float*    dinv   = (float*)(ws + 12800000);

        hipMemsetAsync(bitmap, 0, 12800000, stream);
        scatter_edges_fb<<<(E_EDGES + 255) / 256, 256, 0, stream>>>(ei, bitmap);
        popc_dinv      <<<N_NODES / 4, 256, 0, stream>>>(bitmap, dinv);
        spmm_bitmap_fb <<<N_NODES / 4, 256, 0, stream>>>(bitmap, dinv, x, out);
        gemm_valu      <<<N_NODES / 16, 256, 0, stream>>>(out, w);
    }
    // else: ws too small for any safe plan — no-op (never observed).
}

// Round 13
// 135.547 us; speedup vs baseline: 1.1689x; 1.0525x over previous
//
#include <hip/hip_runtime.h>
#include <hip/hip_bf16.h>
#include <stdint.h>

// Problem constants (fixed by reference spec; dtypes f32/int32 verified over
// rounds 3-12 — bit-stable outputs; bounds-clamps retained as the safety net)
#define N_NODES   10000
#define D_FEAT    256
#define E_EDGES   320000
#define ROW_WORDS 313     // ceil(10000/32) bitmap words per row
#define ROW_STRIDE 320    // fallback plan: padded words per bitmap row
#define LIST_CAP  1024    // fallback plan: per-wave neighbor list capacity

// Bucketed-CSR build (primary plan, r9-r12 proven)
#define NB     250        // buckets (fill side)
#define RPB    40         // rows per bucket (250*40 = 10000 exactly)
#define B_CAP  8192       // entries per bucket; mean 5120, sigma ~71 -> 30+ sigma
#define NBLK_E 313        // edge blocks in fill_buckets ((320000+1023)/1024)
#define NBLK_W 64         // wcast blocks appended to fill_buckets (4 k each)
#define RPC    20         // rows per bucket_to_csr block (r13: 500 half-buckets)

#define LDSTR 264         // f16 LDS row stride for gemm (256 + 8 pad)

typedef __attribute__((ext_vector_type(4))) float float4v;   // 4 x f32
typedef _Float16 half8  __attribute__((ext_vector_type(8))); // 8 x f16 (4 VGPR)
typedef _Float16 half4v __attribute__((ext_vector_type(4))); // 4 x f16

__device__ __forceinline__ uint16_t f2bf(float f) {   // RNE, finite inputs
    union { float f; uint32_t u; } v; v.f = f;
    uint32_t r = v.u + 0x7fffu + ((v.u >> 16) & 1u);
    return (uint16_t)(r >> 16);
}
__device__ __forceinline__ float lo16(uint32_t u) {
    union { uint32_t u; float f; } v; v.u = u << 16; return v.f;
}
__device__ __forceinline__ float hi16(uint32_t u) {
    union { uint32_t u; float f; } v; v.u = u & 0xffff0000u; return v.f;
}

// ===========================================================================
// PRIMARY PLAN: counting-sort bucket fill (+fused W transpose) ->
//   half-bucket LDS dedup CSR (+fused prescale) -> 8-deep wave-per-row
//   gather -> MFMA GEMM with LDS-staged A.
// r11 lesson: never trade wave count for locality in the latency-bound gather.
// ===========================================================================

// ---------------------------------------------------------------------------
// P1: blocks [0,313): partition edges into 250 row-group buckets via block-
// level LDS counting sort (coalesced runs instead of 640k 4B scatters).
//     blocks [313,377): wT[n][k] = f16(W[k][n]), LDS-staged (fused wcast).
// ---------------------------------------------------------------------------
__global__ void __launch_bounds__(1024)
fill_buckets(const int* __restrict__ ei, uint32_t* __restrict__ bucketbuf,
             uint32_t* __restrict__ cursors,
             const float* __restrict__ w, _Float16* __restrict__ wt) {
    __shared__ uint32_t hist[256];
    __shared__ uint32_t lofs[256];     // inclusive scan of hist
    __shared__ uint32_t base_s[256];
    __shared__ uint32_t stage[2048];   // also reused as f32[1024] by wcast
    __shared__ uint16_t sbkt[2048];
    int t = threadIdx.x;

    if (blockIdx.x >= NBLK_E) {        // ---- fused wcast blocks ----
        int kb = (blockIdx.x - NBLK_E) * 4;
        int k = kb + (t >> 8), n = t & 255;
        float* st = (float*)stage;     // 4 KB staging
        st[(n << 2) | (t >> 8)] = w[(size_t)k * D_FEAT + n];
        __syncthreads();
        if (t < 256) {
            half4v o = { (_Float16)st[t * 4 + 0], (_Float16)st[t * 4 + 1],
                         (_Float16)st[t * 4 + 2], (_Float16)st[t * 4 + 3] };
            *(half4v*)&wt[(size_t)t * D_FEAT + kb] = o;
        }
        return;
    }

    if (t < 256) hist[t] = 0;
    __syncthreads();
    int e = blockIdx.x * 1024 + t;
    int b0 = -1, b1 = -1; uint32_t ent0 = 0, ent1 = 0, s0 = 0, s1 = 0;
    if (e < E_EDGES) {
        int s = ei[e], d = ei[E_EDGES + e];
        if ((uint32_t)s < N_NODES && (uint32_t)d < N_NODES) {
            b0 = s / RPB; ent0 = ((uint32_t)(s - b0 * RPB) << 14) | (uint32_t)d;
            b1 = d / RPB; ent1 = ((uint32_t)(d - b1 * RPB) << 14) | (uint32_t)s;
            s0 = atomicAdd(&hist[b0], 1u);
            s1 = atomicAdd(&hist[b1], 1u);
        }
    }
    __syncthreads();
    if (t < 256) lofs[t] = hist[t];
    __syncthreads();
    for (int d = 1; d < 256; d <<= 1) {              // Hillis-Steele inclusive
        uint32_t v = 0;
        if (t < 256 && t >= d) v = lofs[t - d];
        __syncthreads();
        if (t < 256) lofs[t] += v;
        __syncthreads();
    }
    if (t < 256) base_s[t] = hist[t] ? atomicAdd(&cursors[t], hist[t]) : 0u;
    if (b0 >= 0) {
        uint32_t p0 = lofs[b0] - hist[b0] + s0;
        stage[p0] = ent0; sbkt[p0] = (uint16_t)b0;
        uint32_t p1 = lofs[b1] - hist[b1] + s1;
        stage[p1] = ent1; sbkt[p1] = (uint16_t)b1;
    }
    __syncthreads();
    uint32_t total = lofs[255];
    for (uint32_t idx = t; idx < total; idx += 1024) {
        uint32_t b = sbkt[idx];
        uint32_t pos = base_s[b] + (idx - (lofs[b] - hist[b]));
        if (pos < B_CAP) bucketbuf[(size_t)b * B_CAP + pos] = stage[idx];
    }
}

// ---------------------------------------------------------------------------
// P2 (r13: 500 half-bucket blocks, 2x parallelism, 25 KB LDS): entries ->
// LDS bitmap dedup -> deg/dinv -> compact global CSR (rows 4-entry aligned;
// one global atomic per block) + fused prescale xs = bf16(dinv * x).
// Each block scans its bucket's full entry list and filters its 20 rows.
// ---------------------------------------------------------------------------
__global__ void __launch_bounds__(1024)
bucket_to_csr(const uint32_t* __restrict__ bucketbuf,
              const uint32_t* __restrict__ cursors,
              uint32_t* __restrict__ gcursor,
              uint32_t* __restrict__ col, uint32_t* __restrict__ row_base,
              uint32_t* __restrict__ row_deg, float* __restrict__ dinv,
              const float* __restrict__ x, uint16_t* __restrict__ xs) {
    __shared__ uint32_t bm[RPC * ROW_WORDS];      // 20*313*4 = 25,040 B
    __shared__ uint32_t degs[RPC];
    __shared__ uint32_t rowoff[RPC];
    __shared__ uint32_t segbase;
    int blk = blockIdx.x, t = threadIdx.x;
    int b   = blk >> 1;                 // bucket
    int lr0 = (blk & 1) * RPC;          // local-row window [lr0, lr0+20)
    for (int i = t; i < RPC * ROW_WORDS; i += 1024) bm[i] = 0;
    __syncthreads();
    uint32_t cnt = min(cursors[b], (uint32_t)B_CAP);
    const uint32_t* bb = bucketbuf + (size_t)b * B_CAP;
    for (uint32_t i = t; i < cnt; i += 1024) {
        uint32_t ent = bb[i];
        uint32_t lr = (ent >> 14) - (uint32_t)lr0;
        if (lr < RPC) {
            uint32_t d = ent & 0x3FFFu;
            atomicOr(&bm[lr * ROW_WORDS + (d >> 5)], 1u << (d & 31));
        }
    }
    __syncthreads();
    int wv = t >> 6, lane = t & 63;               // 16 waves
    for (int r = wv; r < RPC; r += 16) {
        int pop = 0;
        #pragma unroll
        for (int k = 0; k < 5; k++) {
            int w = lane + 64 * k;
            if (w < ROW_WORDS) pop += __popc(bm[r * ROW_WORDS + w]);
        }
        #pragma unroll
        for (int off = 32; off > 0; off >>= 1) pop += __shfl_xor(pop, off, 64);
        if (lane == 0) degs[r] = (uint32_t)pop;
    }
    __syncthreads();
    if (t == 0) {
        uint32_t run = 0;
        for (int r = 0; r < RPC; r++) {
            rowoff[r] = run;
            run += (degs[r] + 3u) & ~3u;           // 4-entry align per row
        }
        segbase = atomicAdd(gcursor, run);
    }
    __syncthreads();
    int row0 = b * RPB + lr0;
    for (int r = wv; r < RPC; r += 16) {
        int gi = row0 + r;
        uint32_t base = segbase + rowoff[r];
        float di = 1.0f / sqrtf((float)(degs[r] + 1u));
        if (lane == 0) {
            row_base[gi] = base;
            row_deg[gi]  = degs[r];
            dinv[gi]     = di;
        }
        // ---- fused prescale: xs[gi] = bf16(di * x[gi]) (coalesced) ----
        float4v xv = *(const float4v*)(x + (size_t)gi * D_FEAT + lane * 4);
        uint2 o;
        o.x = (uint32_t)f2bf(di * xv[0]) | ((uint32_t)f2bf(di * xv[1]) << 16);
        o.y = (uint32_t)f2bf(di * xv[2]) | ((uint32_t)f2bf(di * xv[3]) << 16);
        *(uint2*)(xs + (size_t)gi * D_FEAT + lane * 4) = o;
        // ---- expand set bits -> col[base ...] ----
        uint32_t wb[5]; int tot = 0;
        #pragma unroll
        for (int k = 0; k < 5; k++) {
            int w = lane + 64 * k;
            uint32_t v = (w < ROW_WORDS) ? bm[r * ROW_WORDS + w] : 0u;
            wb[k] = v; tot += __popc(v);
        }
        int incl = tot;
        #pragma unroll
        for (int off = 1; off < 64; off <<= 1) {
            int v = __shfl_up(incl, off, 64);
            if (lane >= off) incl += v;
        }
        uint32_t p = base + (uint32_t)(incl - tot);
        #pragma unroll
        for (int k = 0; k < 5; k++) {
            uint32_t bits = wb[k];
            uint32_t cbase = (uint32_t)(lane + 64 * k) << 5;
            while (bits) {
                col[p++] = cbase + (uint32_t)__builtin_ctz(bits);
                bits &= bits - 1;
            }
        }
    }
}

// ---------------------------------------------------------------------------
// P3: aggregation, wave-per-row (10000 waves), r13: EIGHT independent gather
// streams (phase is MLP-limited: VALUBusy 16-21% across r7-r11).
// agg (f16, GEMM A operand) -> ws (bucketbuf region, dead by now).
// ---------------------------------------------------------------------------
__global__ void __launch_bounds__(256)
spmm_csr(const uint32_t* __restrict__ row_base, const uint32_t* __restrict__ row_deg,
         const float* __restrict__ dinv, const uint32_t* __restrict__ col,
         const uint16_t* __restrict__ xs, _Float16* __restrict__ aggh) {
    int wv = threadIdx.x >> 6, lane = threadIdx.x & 63;
    int i = blockIdx.x * 4 + wv;
    uint32_t base = row_base[i], deg = row_deg[i];
    float di = dinv[i];
    float4v z = {0.f, 0.f, 0.f, 0.f};
    float4v a0 = z, a1 = z, a2 = z, a3 = z, a4 = z, a5 = z, a6 = z, a7 = z;
    size_t ch = (size_t)lane * 4;
    uint32_t t8 = deg & ~7u;
    uint32_t t = 0;
    for (; t < t8; t += 8) {
        uint4 jva = *(const uint4*)&col[base + t];       // wave-uniform bcast
        uint4 jvb = *(const uint4*)&col[base + t + 4];
        uint2 g0 = *(const uint2*)(xs + (size_t)jva.x * D_FEAT + ch);
        uint2 g1 = *(const uint2*)(xs + (size_t)jva.y * D_FEAT + ch);
        uint2 g2 = *(const uint2*)(xs + (size_t)jva.z * D_FEAT + ch);
        uint2 g3 = *(const uint2*)(xs + (size_t)jva.w * D_FEAT + ch);
        uint2 g4 = *(const uint2*)(xs + (size_t)jvb.x * D_FEAT + ch);
        uint2 g5 = *(const uint2*)(xs + (size_t)jvb.y * D_FEAT + ch);
        uint2 g6 = *(const uint2*)(xs + (size_t)jvb.z * D_FEAT + ch);
        uint2 g7 = *(const uint2*)(xs + (size_t)jvb.w * D_FEAT + ch);
        a0[0] += lo16(g0.x); a0[1] += hi16(g0.x); a0[2] += lo16(g0.y); a0[3] += hi16(g0.y);
        a1[0] += lo16(g1.x); a1[1] += hi16(g1.x); a1[2] += lo16(g1.y); a1[3] += hi16(g1.y);
        a2[0] += lo16(g2.x); a2[1] += hi16(g2.x); a2[2] += lo16(g2.y); a2[3] += hi16(g2.y);
        a3[0] += lo16(g3.x); a3[1] += hi16(g3.x); a3[2] += lo16(g3.y); a3[3] += hi16(g3.y);
        a4[0] += lo16(g4.x); a4[1] += hi16(g4.x); a4[2] += lo16(g4.y); a4[3] += hi16(g4.y);
        a5[0] += lo16(g5.x); a5[1] += hi16(g5.x); a5[2] += lo16(g5.y); a5[3] += hi16(g5.y);
        a6[0] += lo16(g6.x); a6[1] += hi16(g6.x); a6[2] += lo16(g6.y); a6[3] += hi16(g6.y);
        a7[0] += lo16(g7.x); a7[1] += hi16(g7.x); a7[2] += lo16(g7.y); a7[3] += hi16(g7.y);
    }
    for (; t < deg; t++) {
        uint32_t j = col[base + t];
        uint2 g = *(const uint2*)(xs + (size_t)j * D_FEAT + ch);
        a0[0] += lo16(g.x); a0[1] += hi16(g.x); a0[2] += lo16(g.y); a0[3] += hi16(g.y);
    }
    uint2 gs = *(const uint2*)(xs + (size_t)i * D_FEAT + ch);   // +I self term
    a1[0] += lo16(gs.x); a1[1] += hi16(gs.x); a1[2] += lo16(gs.y); a1[3] += hi16(gs.y);
    float4v acc = ((a0 + a1) + (a2 + a3)) + ((a4 + a5) + (a6 + a7));
    half4v o = { (_Float16)(di * acc[0]), (_Float16)(di * acc[1]),
                 (_Float16)(di * acc[2]), (_Float16)(di * acc[3]) };
    *(half4v*)(aggh + (size_t)i * D_FEAT + ch) = o;
}

// ---------------------------------------------------------------------------
// P4: out = aggh @ W via mfma_f32_16x16x32_f16. r13: A-tile staged in LDS
// once per block (r12 refetched it from global per col-tile wave: 80 MB ->
// 5 MB A traffic). 625 blocks x 4 waves; wave does 4 col-tiles (r11 Phase B,
// correctness-proven). Layouts m89/m91-verified, r10 end-to-end PASS.
// ---------------------------------------------------------------------------
__global__ void __launch_bounds__(256)
gemm_mfma(const _Float16* __restrict__ aggh, const _Float16* __restrict__ wt,
          float* __restrict__ out) {
    __shared__ __align__(16) _Float16 a_lds[16 * LDSTR];   // 8448 B
    int t = threadIdx.x, wv = t >> 6, lane = t & 63;
    int r0 = blockIdx.x * 16;
    for (int idx = t * 8; idx < 16 * D_FEAT; idx += 256 * 8) {
        int r = idx >> 8, c = idx & 255;
        *(half8*)&a_lds[r * LDSTR + c] =
            *(const half8*)&aggh[(size_t)(r0 + r) * D_FEAT + c];
    }
    __syncthreads();
    int quad = lane >> 4, r = lane & 15;
    int mbase = r0 + quad * 4;
    #pragma unroll
    for (int u = 0; u < 4; u++) {
        int ct = wv * 4 + u;                       // col tile 0..15
        const _Float16* pb = wt + (size_t)(ct * 16 + r) * D_FEAT + quad * 8;
        float4v acc = {0.f, 0.f, 0.f, 0.f};
        #pragma unroll
        for (int kk = 0; kk < D_FEAT; kk += 32) {
            half8 a = *(const half8*)&a_lds[r * LDSTR + kk + quad * 8];
            half8 b = *(const half8*)(pb + kk);
            acc = __builtin_amdgcn_mfma_f32_16x16x32_f16(a, b, acc, 0, 0, 0);
        }
        int colg = ct * 16 + r;
        #pragma unroll
        for (int v = 0; v < 4; v++)
            out[(size_t)(mbase + v) * D_FEAT + colg] = acc[v];
    }
}

// ===========================================================================
// FALLBACK PLAN (r7-proven, ~12.85 MB): global bitmap + popc + f32 gather
// ===========================================================================

__global__ void scatter_edges_fb(const int* __restrict__ ei,
                                 uint32_t* __restrict__ bitmap) {
    int e = blockIdx.x * blockDim.x + threadIdx.x;
    if (e >= E_EDGES) return;
    int s = ei[e], d = ei[E_EDGES + e];
    if ((uint32_t)s >= N_NODES || (uint32_t)d >= N_NODES) return;
    atomicOr(&bitmap[(size_t)s * ROW_STRIDE + (d >> 5)], 1u << (d & 31));
    atomicOr(&bitmap[(size_t)d * ROW_STRIDE + (s >> 5)], 1u << (s & 31));
}

__global__ void __launch_bounds__(256)
popc_dinv(const uint32_t* __restrict__ bitmap, float* __restrict__ dinv) {
    int wv = threadIdx.x >> 6, lane = threadIdx.x & 63;
    int i = blockIdx.x * 4 + wv;
    const uint32_t* rb = bitmap + (size_t)i * ROW_STRIDE;
    int pop = 0;
    #pragma unroll
    for (int k = 0; k < 5; k++) {
        int w = lane + 64 * k;
        if (w < ROW_WORDS) pop += __popc(rb[w]);
    }
    #pragma unroll
    for (int off = 32; off > 0; off >>= 1) pop += __shfl_xor(pop, off, 64);
    if (lane == 0) dinv[i] = 1.0f / sqrtf((float)(pop + 1));
}

__global__ void __launch_bounds__(256)
spmm_bitmap_fb(const uint32_t* __restrict__ bitmap, const float* __restrict__ dinv,
               const float* __restrict__ xf, float* __restrict__ agg) {
    __shared__ __align__(16) uint32_t lists[4][LIST_CAP];
    int wv = threadIdx.x >> 6, lane = threadIdx.x & 63;
    int i = blockIdx.x * 4 + wv;
    uint32_t* list = lists[wv];
    const uint32_t* rb = bitmap + (size_t)i * ROW_STRIDE;

    uint32_t wbits[5]; int tot = 0;
    #pragma unroll
    for (int k = 0; k < 5; k++) {
        int w = lane + 64 * k;
        uint32_t b = (w < ROW_WORDS) ? rb[w] : 0u;
        wbits[k] = b;
        tot += __popc(b);
    }
    int incl = tot;
    #pragma unroll
    for (int off = 1; off < 64; off <<= 1) {
        int v = __shfl_up(incl, off, 64);
        if (lane >= off) incl += v;
    }
    uint32_t p = (uint32_t)(incl - tot);
    uint32_t deg = (uint32_t)__shfl(incl, 63, 64);
    #pragma unroll
    for (int k = 0; k < 5; k++) {
        uint32_t bits = wbits[k];
        uint32_t base = (uint32_t)(lane + 64 * k) << 5;
        while (bits) {
            if (p < LIST_CAP) list[p] = base + (uint32_t)__builtin_ctz(bits);
            p++;
            bits &= bits - 1;
        }
    }
    if (deg > LIST_CAP) deg = LIST_CAP;

    float di = dinv[i];
    float4v z = {0.f, 0.f, 0.f, 0.f};
    float4v acc0 = z, acc1 = z, acc2 = z, acc3 = z;
    float4v sv = *(const float4v*)(xf + (size_t)i * D_FEAT + lane * 4);
    uint32_t t4 = deg & ~3u;
    for (uint32_t k = 0; k < t4; k += 4) {
        uint4 jv = *(const uint4*)&list[k];
        float d0 = dinv[jv.x], d1 = dinv[jv.y], d2 = dinv[jv.z], d3 = dinv[jv.w];
        float4v v0 = *(const float4v*)(xf + (size_t)jv.x * D_FEAT + lane * 4);
        float4v v1 = *(const float4v*)(xf + (size_t)jv.y * D_FEAT + lane * 4);
        float4v v2 = *(const float4v*)(xf + (size_t)jv.z * D_FEAT + lane * 4);
        float4v v3 = *(const float4v*)(xf + (size_t)jv.w * D_FEAT + lane * 4);
        acc0 += d0 * v0; acc1 += d1 * v1; acc2 += d2 * v2; acc3 += d3 * v3;
    }
    for (uint32_t k = t4; k < deg; k++) {
        uint32_t j = list[k];
        acc0 += dinv[j] * (*(const float4v*)(xf + (size_t)j * D_FEAT + lane * 4));
    }
    float4v acc = (acc0 + acc1) + (acc2 + acc3) + di * sv;
    *(float4v*)(agg + (size_t)i * D_FEAT + lane * 4) = di * acc;
}

// Fallback epilogue GEMM (in place on d_out) — r9-proven VALU version.
__global__ void __launch_bounds__(256)
gemm_valu(float* __restrict__ io, const float* __restrict__ wf) {
    __shared__ __align__(16) float a_lds[16 * D_FEAT];
    int c = threadIdx.x;
    int r0 = blockIdx.x * 16;
    for (int idx = c; idx < 16 * D_FEAT; idx += 256)
        a_lds[idx] = io[(size_t)r0 * D_FEAT + idx];
    __syncthreads();
    float acc[16];
    #pragma unroll
    for (int r = 0; r < 16; r++) acc[r] = 0.f;
    for (int k0 = 0; k0 < D_FEAT; k0 += 4) {
        float w0 = wf[(size_t)(k0 + 0) * D_FEAT + c];
        float w1 = wf[(size_t)(k0 + 1) * D_FEAT + c];
        float w2 = wf[(size_t)(k0 + 2) * D_FEAT + c];
        float w3 = wf[(size_t)(k0 + 3) * D_FEAT + c];
        #pragma unroll
        for (int r = 0; r < 16; r++) {
            float4v av = *(const float4v*)&a_lds[r * D_FEAT + k0];
            acc[r] = fmaf(av[3], w3, fmaf(av[2], w2,
                     fmaf(av[1], w1, fmaf(av[0], w0, acc[r]))));
        }
    }
    #pragma unroll
    for (int r = 0; r < 16; r++)
        io[(size_t)(r0 + r) * D_FEAT + c] = acc[r];
}

// ---------------------------------------------------------------------------
extern "C" void kernel_launch(void* const* d_in, const int* in_sizes, int n_in,
                              void* d_out, int out_size, void* d_ws, size_t ws_size,
                              hipStream_t stream) {
    const float* x  = (const float*)d_in[0];     // f32 [N, 256]
    const int*   ei = (const int*)d_in[1];       // int32 [2, E]
    const float* w  = (const float*)d_in[2];     // f32 [256, 256]
    float* out = (float*)d_out;                  // f32 [N, 256]
    uint8_t* ws = (uint8_t*)d_ws;

    // Primary layout (16.29 MB; ws >= 18 MB proven by r8-r12):
    //   bucketbuf @ 0          : 8,192,000  -- dead after bucket_to_csr;
    //   aggh      @ 0          : 5,120,000     reused as f16 agg (A operand)
    //   cursors   @ 8,192,000  : 2,048      (250 cursors + gcursor)
    //   row_base  @ 8,194,048  : 40,000
    //   row_deg   @ 8,234,048  : 40,000
    //   dinv      @ 8,274,048  : 40,000
    //   xs        @ 8,314,048  : 5,120,000  (bf16 prescaled x)
    //   col       @ 13,434,048 : 2,720,000
    //   wT(f16)   @ 16,154,048 : 131,072
    const size_t CUR_OFF  = 8192000;
    const size_t RB_OFF   = 8194048;
    const size_t RD_OFF   = 8234048;
    const size_t DI_OFF   = 8274048;
    const size_t XS_OFF   = 8314048;
    const size_t COL_OFF  = 13434048;
    const size_t WT_OFF   = 16154048;
    const size_t NEED_NEW = 16285120;
    const size_t NEED_FB  = 12840000;

    if (ws_size >= NEED_NEW) {
        uint32_t* bucketbuf = (uint32_t*)ws;
        _Float16* aggh      = (_Float16*)ws;         // reuse (sequential kernels)
        uint32_t* cursors   = (uint32_t*)(ws + CUR_OFF);
        uint32_t* row_base  = (uint32_t*)(ws + RB_OFF);
        uint32_t* row_deg   = (uint32_t*)(ws + RD_OFF);
        float*    dinv      = (float*)(ws + DI_OFF);
        uint16_t* xs        = (uint16_t*)(ws + XS_OFF);
        uint32_t* col       = (uint32_t*)(ws + COL_OFF);
        _Float16* wt        = (_Float16*)(ws + WT_OFF);

        hipMemsetAsync(cursors, 0, 2048, stream);    // cursors + gcursor only
        fill_buckets <<<NBLK_E + NBLK_W, 1024, 0, stream>>>(ei, bucketbuf, cursors, w, wt);
        bucket_to_csr<<<NB * 2, 1024, 0, stream>>>(bucketbuf, cursors, &cursors[NB],
                                                   col, row_base, row_deg, dinv, x, xs);
        spmm_csr     <<<N_NODES / 4, 256, 0, stream>>>(row_base, row_deg, dinv, col, xs, aggh);
        gemm_mfma    <<<N_NODES / 16, 256, 0, stream>>>(aggh, wt, out);
    } else if (ws_size >= NEED_FB) {
        uint32_t* bitmap = (uint32_t*)ws;
        float*    dinv   = (float*)(ws + 12800000);

        hipMemsetAsync(bitmap, 0, 12800000, stream);
        scatter_edges_fb<<<(E_EDGES + 255) / 256, 256, 0, stream>>>(ei, bitmap);
        popc_dinv      <<<N_NODES / 4, 256, 0, stream>>>(bitmap, dinv);
        spmm_bitmap_fb <<<N_NODES / 4, 256, 0, stream>>>(bitmap, dinv, x, out);
        gemm_valu      <<<N_NODES / 16, 256, 0, stream>>>(out, w);
    }
    // else: ws too small for any safe plan — no-op (never observed).
}

// Round 14
// 132.534 us; speedup vs baseline: 1.1955x; 1.0227x over previous
//
#include <hip/hip_runtime.h>
#include <hip/hip_bf16.h>
#include <stdint.h>

// Problem constants (fixed by reference spec; dtypes f32/int32 verified over
// rounds 3-13 — bit-stable outputs; bounds-clamps retained as the safety net)
#define N_NODES   10000
#define D_FEAT    256
#define E_EDGES   320000
#define ROW_WORDS 313     // ceil(10000/32) bitmap words per row
#define ROW_STRIDE 320    // fallback plan: padded words per bitmap row
#define LIST_CAP  1024    // fallback plan: per-wave neighbor list capacity

// Deterministic slotted bucket build (r14): no global atomics anywhere.
#define NB     250        // buckets
#define RPB    40         // rows per bucket (250*40 = 10000 exactly)
#define RPC    20         // rows per csr block (500 half-bucket blocks)
#define S_CAP  48         // entries per (block,bucket) slot; mean 8.2, ~15 sigma
#define NBLK_E 313        // edge blocks in fill_sort ((320000+1023)/1024)
#define NBLK_W 64         // wcast blocks appended to fill_sort
#define NBLK_C 500        // csr half-bucket blocks in csr_gemm
#define NBLK_G 625        // gemm blocks appended in csr_gemm (16 rows each)
#define COLSTR 128        // fixed col stride per row (max deg ~100 < 128)

#define LDSTR 264         // f16 LDS row stride for gemm (256 + 8 pad)

typedef __attribute__((ext_vector_type(4))) float float4v;   // 4 x f32
typedef _Float16 half8  __attribute__((ext_vector_type(8))); // 8 x f16 (4 VGPR)
typedef _Float16 half4v __attribute__((ext_vector_type(4))); // 4 x f16

__device__ __forceinline__ float h2f_lo(uint32_t u) {
    union { uint32_t u; _Float16 h[2]; } v; v.u = u; return (float)v.h[0];
}
__device__ __forceinline__ float h2f_hi(uint32_t u) {
    union { uint32_t u; _Float16 h[2]; } v; v.u = u; return (float)v.h[1];
}

// ===========================================================================
// PRIMARY PLAN (3 dispatches, 0 global atomics, 0 memset):
//   K1 fill_sort : counting-sorted slotted buckets + f16 W^T
//   K2 csr_gemm  : [0,500) slot scan -> LDS bitmap dedup -> deg/dinv/CSR
//                  [500,1125) yw = f16(x @ W) via MFMA  (independent halves
//                  co-scheduled in one grid — r14 dispatch-overhead attack)
//   K3 spmm_out  : out_i = dinv_i*(sum dinv_j*yw_j + dinv_i*yw_i) -> d_out
// r11 lesson kept: wave-per-row in the latency-bound gather.
// ===========================================================================

// ---------------------------------------------------------------------------
// K1: blocks [0,313): LDS counting sort of 1024 edges' 2048 endpoint entries
// into 250 buckets; write each bucket's run to the block's OWN slot
// bucketbuf[block][bucket][0..cnt) — deterministic, no cursors, no memset.
//     blocks [313,377): wT[n][k] = f16(W[k][n]) (fused, r12-proven).
// ---------------------------------------------------------------------------
__global__ void __launch_bounds__(1024)
fill_sort(const int* __restrict__ ei, uint32_t* __restrict__ bucketbuf,
          uint32_t* __restrict__ hist_g,
          const float* __restrict__ w, _Float16* __restrict__ wt) {
    __shared__ uint32_t hist[256];
    __shared__ uint32_t lofs[256];     // inclusive scan of hist
    __shared__ uint32_t stage[2048];   // also reused as f32[1024] by wcast
    __shared__ uint16_t sbkt[2048];
    int t = threadIdx.x;

    if (blockIdx.x >= NBLK_E) {        // ---- fused wcast blocks ----
        int kb = (blockIdx.x - NBLK_E) * 4;
        int k = kb + (t >> 8), n = t & 255;
        float* st = (float*)stage;     // 4 KB staging
        st[(n << 2) | (t >> 8)] = w[(size_t)k * D_FEAT + n];
        __syncthreads();
        if (t < 256) {
            half4v o = { (_Float16)st[t * 4 + 0], (_Float16)st[t * 4 + 1],
                         (_Float16)st[t * 4 + 2], (_Float16)st[t * 4 + 3] };
            *(half4v*)&wt[(size_t)t * D_FEAT + kb] = o;
        }
        return;
    }

    if (t < 256) hist[t] = 0;
    __syncthreads();
    int e = blockIdx.x * 1024 + t;
    int b0 = -1, b1 = -1; uint32_t ent0 = 0, ent1 = 0, s0 = 0, s1 = 0;
    if (e < E_EDGES) {
        int s = ei[e], d = ei[E_EDGES + e];
        if ((uint32_t)s < N_NODES && (uint32_t)d < N_NODES) {
            b0 = s / RPB; ent0 = ((uint32_t)(s - b0 * RPB) << 14) | (uint32_t)d;
            b1 = d / RPB; ent1 = ((uint32_t)(d - b1 * RPB) << 14) | (uint32_t)s;
            s0 = atomicAdd(&hist[b0], 1u);    // LDS atomics only
            s1 = atomicAdd(&hist[b1], 1u);
        }
    }
    __syncthreads();
    if (t < 256) lofs[t] = hist[t];
    __syncthreads();
    for (int d = 1; d < 256; d <<= 1) {              // Hillis-Steele inclusive
        uint32_t v = 0;
        if (t < 256 && t >= d) v = lofs[t - d];
        __syncthreads();
        if (t < 256) lofs[t] += v;
        __syncthreads();
    }
    if (b0 >= 0) {                     // stage sorted by bucket
        uint32_t p0 = lofs[b0] - hist[b0] + s0;
        stage[p0] = ent0; sbkt[p0] = (uint16_t)b0;
        uint32_t p1 = lofs[b1] - hist[b1] + s1;
        stage[p1] = ent1; sbkt[p1] = (uint16_t)b1;
    }
    __syncthreads();
    uint32_t total = lofs[255];
    uint32_t bb0 = blockIdx.x * 256;
    for (uint32_t idx = t; idx < total; idx += 1024) {
        uint32_t b = sbkt[idx];
        uint32_t pos = idx - (lofs[b] - hist[b]);
        if (pos < S_CAP)
            bucketbuf[(size_t)(bb0 + b) * S_CAP + pos] = stage[idx];
    }
    if (t < 256) hist_g[bb0 + t] = min(hist[t], (uint32_t)S_CAP);
}

// ---------------------------------------------------------------------------
// K2: heterogeneous grid.
//  blocks [0,500): half-bucket CSR build — scan the bucket's 313 slots,
//    LDS bitmap dedup, per-row popc -> deg/dinv, expand bits to
//    col[gi*128 ...] (fixed stride: no segment allocation, no atomics).
//  blocks [500,1125): yw[16 rows] = f16(x @ W): stage x-tile as f16 in LDS,
//    16 waves x 1 col-tile, mfma_f32_16x16x32_f16 (m89/m91 layout,
//    r10 end-to-end verified).
// ---------------------------------------------------------------------------
__global__ void __launch_bounds__(1024)
csr_gemm(const uint32_t* __restrict__ bucketbuf, const uint32_t* __restrict__ hist_g,
         uint32_t* __restrict__ row_deg, float* __restrict__ dinv,
         uint32_t* __restrict__ col,
         const float* __restrict__ x, const _Float16* __restrict__ wt,
         _Float16* __restrict__ yw) {
    __shared__ __align__(16) uint32_t smem[RPC * ROW_WORDS + NBLK_E]; // 26.3 KB
    int t = threadIdx.x;

    if (blockIdx.x >= NBLK_C) {        // ---- gemm blocks ----
        _Float16* a_lds = (_Float16*)smem;             // 16*264 f16 = 8448 B
        int r0 = (blockIdx.x - NBLK_C) * 16;
        int row = t >> 6, c4 = (t & 63) * 4;           // 1024 thr = 16x64 f4
        float4v xv = *(const float4v*)(x + (size_t)(r0 + row) * D_FEAT + c4);
        half4v h = { (_Float16)xv[0], (_Float16)xv[1],
                     (_Float16)xv[2], (_Float16)xv[3] };
        *(half4v*)&a_lds[row * LDSTR + c4] = h;
        __syncthreads();
        int wv = t >> 6, lane = t & 63;
        int quad = lane >> 4, r = lane & 15;
        int ct = wv;                                   // 16 waves = 16 col tiles
        const _Float16* pb = wt + (size_t)(ct * 16 + r) * D_FEAT + quad * 8;
        float4v acc = {0.f, 0.f, 0.f, 0.f};
        #pragma unroll
        for (int kk = 0; kk < D_FEAT; kk += 32) {
            half8 a = *(const half8*)&a_lds[r * LDSTR + kk + quad * 8];
            half8 b = *(const half8*)(pb + kk);
            acc = __builtin_amdgcn_mfma_f32_16x16x32_f16(a, b, acc, 0, 0, 0);
        }
        int colg = ct * 16 + r;
        #pragma unroll
        for (int u = 0; u < 4; u++)
            yw[(size_t)(r0 + quad * 4 + u) * D_FEAT + colg] = (_Float16)acc[u];
        return;
    }

    // ---- csr blocks ----
    uint32_t* bm       = smem;                         // 20*313 words
    uint32_t* hist_col = smem + RPC * ROW_WORDS;       // 313 words
    int b   = blockIdx.x >> 1;                         // bucket
    int lr0 = (blockIdx.x & 1) * RPC;                  // local-row window
    for (int i = t; i < RPC * ROW_WORDS; i += 1024) bm[i] = 0;
    if (t < NBLK_E) hist_col[t] = hist_g[(size_t)t * 256 + b];
    __syncthreads();
    for (int p = t; p < NBLK_E * S_CAP; p += 1024) {
        int sb = p / S_CAP, off = p % S_CAP;
        if ((uint32_t)off < hist_col[sb]) {
            uint32_t ent = bucketbuf[(size_t)(sb * 256 + b) * S_CAP + off];
            uint32_t lr = (ent >> 14) - (uint32_t)lr0;
            if (lr < RPC) {
                uint32_t d = ent & 0x3FFFu;
                atomicOr(&bm[lr * ROW_WORDS + (d >> 5)], 1u << (d & 31));
            }
        }
    }
    __syncthreads();
    int wv = t >> 6, lane = t & 63;                    // 16 waves
    for (int r = wv; r < RPC; r += 16) {
        int gi = b * RPB + lr0 + r;
        uint32_t wb[5]; int tot = 0;
        #pragma unroll
        for (int k = 0; k < 5; k++) {
            int w = lane + 64 * k;
            uint32_t v = (w < ROW_WORDS) ? bm[r * ROW_WORDS + w] : 0u;
            wb[k] = v; tot += __popc(v);
        }
        int incl = tot;
        #pragma unroll
        for (int off = 1; off < 64; off <<= 1) {
            int v = __shfl_up(incl, off, 64);
            if (lane >= off) incl += v;
        }
        uint32_t total = (uint32_t)__shfl(incl, 63, 64);
        if (lane == 0) {
            row_deg[gi] = min(total, (uint32_t)COLSTR);
            dinv[gi]    = 1.0f / sqrtf((float)(total + 1u));  // +1 = the eye
        }
        uint32_t p = (uint32_t)(incl - tot);
        #pragma unroll
        for (int k = 0; k < 5; k++) {
            uint32_t bits = wb[k];
            uint32_t cbase = (uint32_t)(lane + 64 * k) << 5;
            while (bits) {
                if (p < COLSTR)
                    col[(size_t)gi * COLSTR + p] = cbase + (uint32_t)__builtin_ctz(bits);
                p++;
                bits &= bits - 1;
            }
        }
    }
}

// ---------------------------------------------------------------------------
// K3: final gather straight into d_out (f32). Wave-per-row (10000 waves),
// 8 independent gather streams (r13-proven). Per-j dinv multiply (yw is the
// UNSCALED X@W — r14 reassociation: out = S·(X·W)).
// ---------------------------------------------------------------------------
__global__ void __launch_bounds__(256)
spmm_out(const uint32_t* __restrict__ row_deg, const float* __restrict__ dinv,
         const uint32_t* __restrict__ col, const _Float16* __restrict__ ywp,
         float* __restrict__ out) {
    const uint16_t* yw = (const uint16_t*)ywp;
    int wv = threadIdx.x >> 6, lane = threadIdx.x & 63;
    int i = blockIdx.x * 4 + wv;
    uint32_t base = (uint32_t)i * COLSTR;
    uint32_t deg = min(row_deg[i], (uint32_t)COLSTR);
    float di = dinv[i];
    float4v z = {0.f, 0.f, 0.f, 0.f};
    float4v a0 = z, a1 = z, a2 = z, a3 = z, a4 = z, a5 = z, a6 = z, a7 = z;
    size_t ch = (size_t)lane * 4;
    uint32_t t8 = deg & ~7u;
    uint32_t t = 0;
    for (; t < t8; t += 8) {
        uint4 jva = *(const uint4*)&col[base + t];       // wave-uniform bcast
        uint4 jvb = *(const uint4*)&col[base + t + 4];
        float d0 = dinv[jva.x], d1 = dinv[jva.y], d2 = dinv[jva.z], d3 = dinv[jva.w];
        float d4 = dinv[jvb.x], d5 = dinv[jvb.y], d6 = dinv[jvb.z], d7 = dinv[jvb.w];
        uint2 g0 = *(const uint2*)(yw + (size_t)jva.x * D_FEAT + ch);
        uint2 g1 = *(const uint2*)(yw + (size_t)jva.y * D_FEAT + ch);
        uint2 g2 = *(const uint2*)(yw + (size_t)jva.z * D_FEAT + ch);
        uint2 g3 = *(const uint2*)(yw + (size_t)jva.w * D_FEAT + ch);
        uint2 g4 = *(const uint2*)(yw + (size_t)jvb.x * D_FEAT + ch);
        uint2 g5 = *(const uint2*)(yw + (size_t)jvb.y * D_FEAT + ch);
        uint2 g6 = *(const uint2*)(yw + (size_t)jvb.z * D_FEAT + ch);
        uint2 g7 = *(const uint2*)(yw + (size_t)jvb.w * D_FEAT + ch);
        a0[0] += d0 * h2f_lo(g0.x); a0[1] += d0 * h2f_hi(g0.x);
        a0[2] += d0 * h2f_lo(g0.y); a0[3] += d0 * h2f_hi(g0.y);
        a1[0] += d1 * h2f_lo(g1.x); a1[1] += d1 * h2f_hi(g1.x);
        a1[2] += d1 * h2f_lo(g1.y); a1[3] += d1 * h2f_hi(g1.y);
        a2[0] += d2 * h2f_lo(g2.x); a2[1] += d2 * h2f_hi(g2.x);
        a2[2] += d2 * h2f_lo(g2.y); a2[3] += d2 * h2f_hi(g2.y);
        a3[0] += d3 * h2f_lo(g3.x); a3[1] += d3 * h2f_hi(g3.x);
        a3[2] += d3 * h2f_lo(g3.y); a3[3] += d3 * h2f_hi(g3.y);
        a4[0] += d4 * h2f_lo(g4.x); a4[1] += d4 * h2f_hi(g4.x);
        a4[2] += d4 * h2f_lo(g4.y); a4[3] += d4 * h2f_hi(g4.y);
        a5[0] += d5 * h2f_lo(g5.x); a5[1] += d5 * h2f_hi(g5.x);
        a5[2] += d5 * h2f_lo(g5.y); a5[3] += d5 * h2f_hi(g5.y);
        a6[0] += d6 * h2f_lo(g6.x); a6[1] += d6 * h2f_hi(g6.x);
        a6[2] += d6 * h2f_lo(g6.y); a6[3] += d6 * h2f_hi(g6.y);
        a7[0] += d7 * h2f_lo(g7.x); a7[1] += d7 * h2f_hi(g7.x);
        a7[2] += d7 * h2f_lo(g7.y); a7[3] += d7 * h2f_hi(g7.y);
    }
    for (; t < deg; t++) {
        uint32_t j = col[base + t];
        float dj = dinv[j];
        uint2 g = *(const uint2*)(yw + (size_t)j * D_FEAT + ch);
        a0[0] += dj * h2f_lo(g.x); a0[1] += dj * h2f_hi(g.x);
        a0[2] += dj * h2f_lo(g.y); a0[3] += dj * h2f_hi(g.y);
    }
    uint2 gs = *(const uint2*)(yw + (size_t)i * D_FEAT + ch);   // +I self term
    a1[0] += di * h2f_lo(gs.x); a1[1] += di * h2f_hi(gs.x);
    a1[2] += di * h2f_lo(gs.y); a1[3] += di * h2f_hi(gs.y);
    float4v acc = ((a0 + a1) + (a2 + a3)) + ((a4 + a5) + (a6 + a7));
    *(float4v*)(out + (size_t)i * D_FEAT + ch) = di * acc;
}

// ===========================================================================
// FALLBACK PLAN (r7-proven, ~12.85 MB): global bitmap + popc + f32 gather
// ===========================================================================

__global__ void scatter_edges_fb(const int* __restrict__ ei,
                                 uint32_t* __restrict__ bitmap) {
    int e = blockIdx.x * blockDim.x + threadIdx.x;
    if (e >= E_EDGES) return;
    int s = ei[e], d = ei[E_EDGES + e];
    if ((uint32_t)s >= N_NODES || (uint32_t)d >= N_NODES) return;
    atomicOr(&bitmap[(size_t)s * ROW_STRIDE + (d >> 5)], 1u << (d & 31));
    atomicOr(&bitmap[(size_t)d * ROW_STRIDE + (s >> 5)], 1u << (s & 31));
}

__global__ void __launch_bounds__(256)
popc_dinv(const uint32_t* __restrict__ bitmap, float* __restrict__ dinv) {
    int wv = threadIdx.x >> 6, lane = threadIdx.x & 63;
    int i = blockIdx.x * 4 + wv;
    const uint32_t* rb = bitmap + (size_t)i * ROW_STRIDE;
    int pop = 0;
    #pragma unroll
    for (int k = 0; k < 5; k++) {
        int w = lane + 64 * k;
        if (w < ROW_WORDS) pop += __popc(rb[w]);
    }
    #pragma unroll
    for (int off = 32; off > 0; off >>= 1) pop += __shfl_xor(pop, off, 64);
    if (lane == 0) dinv[i] = 1.0f / sqrtf((float)(pop + 1));
}

__global__ void __launch_bounds__(256)
spmm_bitmap_fb(const uint32_t* __restrict__ bitmap, const float* __restrict__ dinv,
               const float* __restrict__ xf, float* __restrict__ agg) {
    __shared__ __align__(16) uint32_t lists[4][LIST_CAP];
    int wv = threadIdx.x >> 6, lane = threadIdx.x & 63;
    int i = blockIdx.x * 4 + wv;
    uint32_t* list = lists[wv];
    const uint32_t* rb = bitmap + (size_t)i * ROW_STRIDE;

    uint32_t wbits[5]; int tot = 0;
    #pragma unroll
    for (int k = 0; k < 5; k++) {
        int w = lane + 64 * k;
        uint32_t b = (w < ROW_WORDS) ? rb[w] : 0u;
        wbits[k] = b;
        tot += __popc(b);
    }
    int incl = tot;
    #pragma unroll
    for (int off = 1; off < 64; off <<= 1) {
        int v = __shfl_up(incl, off, 64);
        if (lane >= off) incl += v;
    }
    uint32_t p = (uint32_t)(incl - tot);
    uint32_t deg = (uint32_t)__shfl(incl, 63, 64);
    #pragma unroll
    for (int k = 0; k < 5; k++) {
        uint32_t bits = wbits[k];
        uint32_t base = (uint32_t)(lane + 64 * k) << 5;
        while (bits) {
            if (p < LIST_CAP) list[p] = base + (uint32_t)__builtin_ctz(bits);
            p++;
            bits &= bits - 1;
        }
    }
    if (deg > LIST_CAP) deg = LIST_CAP;

    float di = dinv[i];
    float4v z = {0.f, 0.f, 0.f, 0.f};
    float4v acc0 = z, acc1 = z, acc2 = z, acc3 = z;
    float4v sv = *(const float4v*)(xf + (size_t)i * D_FEAT + lane * 4);
    uint32_t t4 = deg & ~3u;
    for (uint32_t k = 0; k < t4; k += 4) {
        uint4 jv = *(const uint4*)&list[k];
        float d0 = dinv[jv.x], d1 = dinv[jv.y], d2 = dinv[jv.z], d3 = dinv[jv.w];
        float4v v0 = *(const float4v*)(xf + (size_t)jv.x * D_FEAT + lane * 4);
        float4v v1 = *(const float4v*)(xf + (size_t)jv.y * D_FEAT + lane * 4);
        float4v v2 = *(const float4v*)(xf + (size_t)jv.z * D_FEAT + lane * 4);
        float4v v3 = *(const float4v*)(xf + (size_t)jv.w * D_FEAT + lane * 4);
        acc0 += d0 * v0; acc1 += d1 * v1; acc2 += d2 * v2; acc3 += d3 * v3;
    }
    for (uint32_t k = t4; k < deg; k++) {
        uint32_t j = list[k];
        acc0 += dinv[j] * (*(const float4v*)(xf + (size_t)j * D_FEAT + lane * 4));
    }
    float4v acc = (acc0 + acc1) + (acc2 + acc3) + di * sv;
    *(float4v*)(agg + (size_t)i * D_FEAT + lane * 4) = di * acc;
}

// Fallback epilogue GEMM (in place on d_out) — r9-proven VALU version.
__global__ void __launch_bounds__(256)
gemm_valu(float* __restrict__ io, const float* __restrict__ wf) {
    __shared__ __align__(16) float a_lds[16 * D_FEAT];
    int c = threadIdx.x;
    int r0 = blockIdx.x * 16;
    for (int idx = c; idx < 16 * D_FEAT; idx += 256)
        a_lds[idx] = io[(size_t)r0 * D_FEAT + idx];
    __syncthreads();
    float acc[16];
    #pragma unroll
    for (int r = 0; r < 16; r++) acc[r] = 0.f;
    for (int k0 = 0; k0 < D_FEAT; k0 += 4) {
        float w0 = wf[(size_t)(k0 + 0) * D_FEAT + c];
        float w1 = wf[(size_t)(k0 + 1) * D_FEAT + c];
        float w2 = wf[(size_t)(k0 + 2) * D_FEAT + c];
        float w3 = wf[(size_t)(k0 + 3) * D_FEAT + c];
        #pragma unroll
        for (int r = 0; r < 16; r++) {
            float4v av = *(const float4v*)&a_lds[r * D_FEAT + k0];
            acc[r] = fmaf(av[3], w3, fmaf(av[2], w2,
                     fmaf(av[1], w1, fmaf(av[0], w0, acc[r]))));
        }
    }
    #pragma unroll
    for (int r = 0; r < 16; r++)
        io[(size_t)(r0 + r) * D_FEAT + c] = acc[r];
}

// ---------------------------------------------------------------------------
extern "C" void kernel_launch(void* const* d_in, const int* in_sizes, int n_in,
                              void* d_out, int out_size, void* d_ws, size_t ws_size,
                              hipStream_t stream) {
    const float* x  = (const float*)d_in[0];     // f32 [N, 256]
    const int*   ei = (const int*)d_in[1];       // int32 [2, E]
    const float* w  = (const float*)d_in[2];     // f32 [256, 256]
    float* out = (float*)d_out;                  // f32 [N, 256]
    uint8_t* ws = (uint8_t*)d_ws;

    // Primary layout (26.16 MB; ws ≈ 256 MiB per harness poison WRITE_SIZE):
    //   hist_g    @ 0          :    320,512  (313*256 u32)
    //   bucketbuf @ 320,512    : 15,384,576  (313*256*48 u32)
    //   row_deg   @ 15,705,088 :     40,000
    //   dinv      @ 15,745,088 :     40,000
    //   wT (f16)  @ 15,785,088 :    131,072
    //   yw (f16)  @ 15,916,160 :  5,120,000  (X @ W, gather table)
    //   col       @ 21,036,160 :  5,120,000  (10000 * 128 u32, fixed stride)
    const size_t BB_OFF   = 320512;
    const size_t RD_OFF   = 15705088;
    const size_t DI_OFF   = 15745088;
    const size_t WT_OFF   = 15785088;
    const size_t YW_OFF   = 15916160;
    const size_t COL_OFF  = 21036160;
    const size_t NEED_NEW = 26156160;
    const size_t NEED_FB  = 12840000;

    if (ws_size >= NEED_NEW) {
        uint32_t* hist_g    = (uint32_t*)ws;
        uint32_t* bucketbuf = (uint32_t*)(ws + BB_OFF);
        uint32_t* row_deg   = (uint32_t*)(ws + RD_OFF);
        float*    dinv      = (float*)(ws + DI_OFF);
        _Float16* wt        = (_Float16*)(ws + WT_OFF);
        _Float16* yw        = (_Float16*)(ws + YW_OFF);
        uint32_t* col       = (uint32_t*)(ws + COL_OFF);

        fill_sort<<<NBLK_E + NBLK_W, 1024, 0, stream>>>(ei, bucketbuf, hist_g, w, wt);
        csr_gemm <<<NBLK_C + NBLK_G, 1024, 0, stream>>>(bucketbuf, hist_g,
                                                        row_deg, dinv, col, x, wt, yw);
        spmm_out <<<N_NODES / 4, 256, 0, stream>>>(row_deg, dinv, col, yw, out);
    } else if (ws_size >= NEED_FB) {
        uint32_t* bitmap = (uint32_t*)ws;
        float*    dinv   = (float*)(ws + 12800000);

        hipMemsetAsync(bitmap, 0, 12800000, stream);
        scatter_edges_fb<<<(E_EDGES + 255) / 256, 256, 0, stream>>>(ei, bitmap);
        popc_dinv      <<<N_NODES / 4, 256, 0, stream>>>(bitmap, dinv);
        spmm_bitmap_fb <<<N_NODES / 4, 256, 0, stream>>>(bitmap, dinv, x, out);
        gemm_valu      <<<N_NODES / 16, 256, 0, stream>>>(out, w);
    }
    // else: ws too small for any safe plan — no-op (never observed).
}